// Round 9
// baseline (3671.110 us; speedup 1.0000x reference)
//
#include <hip/hip_runtime.h>
#include <stdint.h>
#include <stddef.h>

// ---------------- types ----------------
typedef __bf16 bf16;
typedef __bf16 bf16x8 __attribute__((ext_vector_type(8)));
typedef __bf16 bf16x4 __attribute__((ext_vector_type(4)));
typedef float  f32x4  __attribute__((ext_vector_type(4)));
typedef int    v4i    __attribute__((ext_vector_type(4)));

// ---------------- problem constants ----------------
#define NB   64      // batch
#define NS   512     // seq len
#define NE   256     // embed dim
#define NH   256     // lstm hidden
#define NL   5       // lstm layers
#define NGC  256     // gcn hidden
#define FUSION 774   // 2H + GC + 6

__device__ __forceinline__ float sigm(float x) {
    return __fdividef(1.f, 1.f + __expf(-x));
}
__device__ __forceinline__ float tanh_(float x) {
    return __fdividef(2.f, 1.f + __expf(-2.f * x)) - 1.f;
}

// async global->LDS, 16B per lane. LDS dest must be wave-uniform base + lane*16.
__device__ __forceinline__ void gload_lds16(const void* g, void* l) {
    __builtin_amdgcn_global_load_lds(
        (const __attribute__((address_space(1))) void*)g,
        (__attribute__((address_space(3))) void*)l,
        16, 0, 0);
}

// ---------------- f32 -> bf16 convert (vector of 4) ----------------
__global__ void k_cvt(const float* __restrict__ src, bf16* __restrict__ dst, int n4) {
    int i = blockIdx.x * 256 + threadIdx.x;
    if (i >= n4) return;
    f32x4 v = ((const f32x4*)src)[i];
    bf16x4 o;
    o[0] = (bf16)v[0]; o[1] = (bf16)v[1]; o[2] = (bf16)v[2]; o[3] = (bf16)v[3];
    ((bf16x4*)dst)[i] = o;
}

// ---------------- Wih convert + gate-interleave row permute ----------------
// dst row n' = d*1024 + j*4 + g  <-  src row d*1024 + g*256 + j.
__global__ void k_cvt_perm(const float* __restrict__ src, bf16* __restrict__ dst,
                           int K, int nrows) {
    int r = blockIdx.x * 4 + (threadIdx.x >> 6);
    int lane = threadIdx.x & 63;
    if (r >= nrows) return;
    int g = r & 3, j = (r >> 2) & 255;
    int srcrow = (r & ~1023) | (g << 8) | j;
    const float* s = src + (size_t)srcrow * K;
    bf16* dp = dst + (size_t)r * K;
    for (int c = lane * 4; c < K; c += 256) {
        f32x4 v = *(const f32x4*)(s + c);
        bf16x4 o;
        o[0] = (bf16)v[0]; o[1] = (bf16)v[1]; o[2] = (bf16)v[2]; o[3] = (bf16)v[3];
        *(bf16x4*)(dp + c) = o;
    }
}

// bias permute to match: pb[l][n'] = src[l][d*1024 + g*256 + j]
__global__ void k_perm_bias(const float* __restrict__ b0, const float* __restrict__ bL,
                            float* __restrict__ pb) {
    int i = blockIdx.x * 256 + threadIdx.x;   // < 10240
    int r = i & 2047;
    int layer = i >> 11;
    int g = r & 3, j = (r >> 2) & 255, dh = r >> 10;
    int srcidx = dh * 1024 + g * 256 + j;
    float v = (layer == 0) ? b0[srcidx] : bL[(size_t)(layer - 1) * 2048 + srcidx];
    pb[i] = v;
}

// ---------------- embedding gather (f32 + bf16 copies) ----------------
__global__ void k_embed(const int* __restrict__ seq, const float* __restrict__ table,
                        float* __restrict__ ef, bf16* __restrict__ eb) {
    int t  = blockIdx.x * 256 + threadIdx.x;  // < 64*512*64
    int bs = t >> 6;
    int c4 = (t & 63) << 2;
    int row = seq[bs];
    f32x4 v = *(const f32x4*)(table + (size_t)row * NE + c4);
    *(f32x4*)(ef + (size_t)bs * NE + c4) = v;
    bf16x4 o;
    o[0] = (bf16)v[0]; o[1] = (bf16)v[1]; o[2] = (bf16)v[2]; o[3] = (bf16)v[3];
    *(bf16x4*)(eb + (size_t)bs * NE + c4) = o;
}

// ---------------- 512-thread 128x128 GEMM tile: C_bf16[M][2048] = A*W^T + bias ----------------
// 8 waves: (wm = wave>>1 in 0..3, wn = wave&1). Same fragment math as the
// R5-verified 256-thread tile, rows split 32/wave instead of 64.
__device__ __forceinline__ void gemm_tile512(
    const bf16* __restrict__ A, const bf16* __restrict__ W,
    const float* __restrict__ bias, bf16* __restrict__ G,
    int K, int m0, int n0, bf16* sA, bf16* sB)
{
    int tid = threadIdx.x;
    int wave = tid >> 6, lane = tid & 63;
    int wm = wave >> 1, wn = wave & 1;
    int l15 = lane & 15, quad = lane >> 4;
    f32x4 acc[2][4] = {};
    const int r0 = tid >> 3;          // 0..63
    const int c0 = (tid & 7) * 8;
    for (int k0 = 0; k0 < K; k0 += 64) {
#pragma unroll
        for (int i = 0; i < 2; i++) {
            gload_lds16(A + (size_t)(m0 + i * 64 + r0) * K + k0 + c0, sA + (i * 512 + tid) * 8);
            gload_lds16(W + (size_t)(n0 + i * 64 + r0) * K + k0 + c0, sB + (i * 512 + tid) * 8);
        }
        __syncthreads();
#pragma unroll
        for (int kk = 0; kk < 2; kk++) {
            bf16x8 af[2], bfr[4];
#pragma unroll
            for (int mt = 0; mt < 2; mt++)
                af[mt] = *(const bf16x8*)(sA + (wm * 32 + mt * 16 + l15) * 64 + kk * 32 + quad * 8);
#pragma unroll
            for (int nt = 0; nt < 4; nt++)
                bfr[nt] = *(const bf16x8*)(sB + (wn * 64 + nt * 16 + l15) * 64 + kk * 32 + quad * 8);
#pragma unroll
            for (int mt = 0; mt < 2; mt++)
#pragma unroll
                for (int nt = 0; nt < 4; nt++)
                    acc[mt][nt] = __builtin_amdgcn_mfma_f32_16x16x32_bf16(af[mt], bfr[nt], acc[mt][nt], 0, 0, 0);
        }
        __syncthreads();
    }
#pragma unroll
    for (int mt = 0; mt < 2; mt++)
#pragma unroll
        for (int nt = 0; nt < 4; nt++) {
            int col = n0 + wn * 64 + nt * 16 + l15;
            float bv = bias[col];
            int row0 = m0 + wm * 32 + mt * 16 + quad * 4;
#pragma unroll
            for (int r4 = 0; r4 < 4; r4++)
                G[(size_t)(row0 + r4) * 2048 + col] = (bf16)(acc[mt][nt][r4] + bv);
        }
}

// ---------------- LSTM-GEMM part 1: chunks {0,3} of every batch ----------------
// grid 2048 = 128 bm x 16 bn. Produces the G rows each direction consumes FIRST
// (fwd: tt 0..127; bwd: tt 384..511). Kernel boundary = full sync before LSTM.
__global__ __launch_bounds__(512, 2)
void k_gemm_lstm03(const bf16* __restrict__ A, const bf16* __restrict__ W,
                   const float* __restrict__ bias, bf16* __restrict__ G, int K) {
    __shared__ __align__(16) bf16 sA[128 * 64];
    __shared__ __align__(16) bf16 sB[128 * 64];
    int bn = blockIdx.x & 15;
    int bmi = blockIdx.x >> 4;                      // 0..127 = batch*2 + {0:c0, 1:c3}
    int bm = (bmi >> 1) * 4 + ((bmi & 1) ? 3 : 0);
    gemm_tile512(A, W, bias, G, K, bm << 7, bn << 7, sA, sB);
}

// ---------------- Whh int8 pre-pack + per-row scales ----------------
__global__ void k_prep_i8(const float* __restrict__ Whh0, const float* __restrict__ WhhL,
                          signed char* __restrict__ Wp8, float* __restrict__ scales) {
    int gw = blockIdx.x * 4 + (threadIdx.x >> 6);   // row id < 10240
    int lane = threadIdx.x & 63;
    int row = gw & 1023;
    int d = (gw >> 10) & 1;
    int layer = gw >> 11;
    const float* src = (layer == 0)
        ? (Whh0 + ((size_t)d * 1024 + row) * 256)
        : (WhhL + (((size_t)(layer - 1) * 2 + d) * 1024 + row) * 256);
    f32x4 v = *(const f32x4*)(src + lane * 4);
    float am = fmaxf(fmaxf(fabsf(v[0]), fabsf(v[1])), fmaxf(fabsf(v[2]), fabsf(v[3])));
#pragma unroll
    for (int off = 32; off >= 1; off >>= 1) am = fmaxf(am, __shfl_xor(am, off));
    am = fmaxf(am, 1e-8f);
    float inv = 127.f / am;
    int q0 = (int)__builtin_rintf(v[0] * inv);
    int q1 = (int)__builtin_rintf(v[1] * inv);
    int q2 = (int)__builtin_rintf(v[2] * inv);
    int q3 = (int)__builtin_rintf(v[3] * inv);
    uint32_t packed = (q0 & 255) | ((q1 & 255) << 8) | ((q2 & 255) << 16) | ((q3 & 255) << 24);
    int g = row >> 8, rem = row & 255;
    int w = rem >> 4, l15r = rem & 15;
    int k = lane * 4;
    int kt = k >> 6, q = (k >> 4) & 3, j = k & 15;
    size_t cell = ((size_t)layer * 2 + d) * 256 + (w * 4 + g) * 4 + kt;
    *(uint32_t*)(Wp8 + cell * 1024 + (q * 16 + l15r) * 16 + j) = packed;
    if (lane == 0)
        scales[((size_t)layer * 2 + d) * 1024 + row] = am * (1.f / (127.f * 127.f));
}

// ---------------- FUSED: LSTM (blocks 0-63) + G chunks {1,2} producer (blocks 64+) ----------------
// LSTM starts immediately (chunks {0,3} committed by k_gemm_lstm03, kernel
// boundary = coherent). Producer blocks write G rows for chunks {1,2} and
// signal flags[bm] with agent-scope release atomics (+threadfence for cross-XCD
// L2 writeback). LSTM waits at t=126/254 (chunk crossings, ~123us in — producers
// (~75us) are long done, so the wait is a no-op check). Spin guards bail at 2^28.
// LDS sized 96KB+ -> 1 block/CU: GEMM blocks never share a CU with LSTM blocks.
__global__ __launch_bounds__(512, 1)
void k_lstm_fused(const bf16* __restrict__ A, const bf16* __restrict__ W,
                  const float* __restrict__ bias, bf16* __restrict__ G,
                  const signed char* __restrict__ Wp8, const float* __restrict__ sc,
                  bf16* __restrict__ io_out, unsigned int* __restrict__ flags, int K)
{
    __shared__ __align__(16) bf16 sA[3 * 128 * 64];   // 48KB (pad -> 1 block/CU)
    __shared__ __align__(16) bf16 sB[3 * 128 * 64];   // 48KB
    __shared__ signed char hs[2][2 * 4 * 80];

    if (blockIdx.x >= 64) {
        // ---- producer: one 128x128 tile of chunks {1,2} ----
        int g = blockIdx.x - 64;                    // 0..2047
        int bn = g & 15;
        int bmi = g >> 4;                           // batch*2 + {0:c1, 1:c2}
        int bm = (bmi >> 1) * 4 + ((bmi & 1) ? 2 : 1);
        gemm_tile512(A, W, bias, G, K, bm << 7, bn << 7, sA, sB);
        __syncthreads();                            // all waves drain vmcnt
        if (threadIdx.x == 0) {
            __threadfence();                        // agent fence: L2 writeback
            __hip_atomic_fetch_add(flags + bm, 1u, __ATOMIC_RELEASE,
                                   __HIP_MEMORY_SCOPE_AGENT);
        }
        return;
    }

    // ---- LSTM (R7-verified structure) ----
    const int d   = blockIdx.x & 1;
    const int bg  = blockIdx.x >> 1;      // 0..31 (batch pair)
    const int tid = threadIdx.x;
    const int w = tid >> 6, lane = tid & 63;
    const int l15 = lane & 15, quad = lane >> 4;
    const int b_loc = quad & 1;           // batch within pair
    const int jg    = quad >> 1;          // j-group select (0/1)
    const int b = bg * 2 + b_loc;         // global batch for this lane
    const int j = (w + jg * 8) * 16 + l15; // hidden index owned by this lane

    // resident weights: 2 j-slices x 4 gates x 4 K-windows x 16B = 128 VGPRs
    v4i Wr[2][4][4];
#pragma unroll
    for (int sl = 0; sl < 2; sl++) {
        const int ws = w + sl * 8;
        const signed char* wb = Wp8 + ((size_t)d * 256 + ws * 16) * 1024 + lane * 16;
#pragma unroll
        for (int g = 0; g < 4; g++)
#pragma unroll
            for (int kt = 0; kt < 4; kt++)
                Wr[sl][g][kt] = *(const v4i*)(wb + (g * 4 + kt) * 1024);
    }
#pragma unroll
    for (int sl = 0; sl < 2; sl++)
#pragma unroll
        for (int g = 0; g < 4; g++)
#pragma unroll
            for (int kt = 0; kt < 4; kt++)
                asm volatile("" : "+v"(Wr[sl][g][kt]));

    float scv[4];
#pragma unroll
    for (int g = 0; g < 4; g++)
        scv[g] = sc[d * 1024 + g * 256 + j];

    const bf16* gbase = G + d * 1024 + j * 4;              // + row*2048
    const size_t iob = (size_t)b * NS * 512 + d * 256 + j; // + tt*512

    const int hwr = (b_loc * 4 + (j >> 6)) * 80 + (j & 63);
    const int hrd = (((l15 >> 2) & 1) * 4 + (l15 & 3)) * 80 + quad * 16;
    const int rr = l15 & 3;

    float cst = 0.f;

    // distance-2 G pipeline (row(t) = b*512 + tt(t), tt = d ? NS-1-t : t)
    bf16x4 gcur = *(const bf16x4*)(gbase + (size_t)(b * 512 + (d ? (NS - 1) : 0)) * 2048);
    bf16x4 gnxt = *(const bf16x4*)(gbase + (size_t)(b * 512 + (d ? (NS - 2) : 1)) * 2048);

    // ---- step 0 (no h yet: gates = G only) ----
    {
        bf16x4 gfut = *(const bf16x4*)(gbase + (size_t)(b * 512 + (d ? (NS - 3) : 2)) * 2048);
        float pi = (float)gcur[0];
        float pg = (float)gcur[2], po = (float)gcur[3];
        float ig = sigm(pi), gc = tanh_(pg), og = sigm(po);
        float c = ig * gc;
        cst = c;
        float hh = og * tanh_(c);
        const int tcur = d ? (NS - 1) : 0;
        io_out[iob + (size_t)tcur * 512] = (bf16)hh;
        hs[0][hwr] = (signed char)(int)__builtin_rintf(hh * 127.f);
        gcur = gnxt; gnxt = gfut;
        asm volatile("s_waitcnt lgkmcnt(0)" ::: "memory");
        __builtin_amdgcn_s_barrier();
        asm volatile("" ::: "memory");
    }

    for (int t = 1; t < NS; t++) {
        // chunk-crossing wait (only chunks 1,2 come from the in-kernel producers)
        if ((t & 127) == 126 && t + 2 < NS) {
            int ch = (d ? (NS - 3 - t) : (t + 2)) >> 7;
            if (ch == 1 || ch == 2) {
                if (tid == 0) {
                    unsigned gd = 0;
                    while (__hip_atomic_load(flags + ((bg * 2) * 4 + ch),
                                             __ATOMIC_RELAXED, __HIP_MEMORY_SCOPE_AGENT) < 16u) {
                        if (++gd > (1u << 28)) break;
                    }
                    gd = 0;
                    while (__hip_atomic_load(flags + ((bg * 2 + 1) * 4 + ch),
                                             __ATOMIC_RELAXED, __HIP_MEMORY_SCOPE_AGENT) < 16u) {
                        if (++gd > (1u << 28)) break;
                    }
                }
                __syncthreads();
                __threadfence();   // acquire: invalidate caches before reading new chunk
            }
        }

        const int rb = (t + 1) & 1, wbuf = t & 1;

        // prefetch G for step t+2
        bf16x4 gfut = gcur;
        if (t + 2 < NS) {
            const int tt2 = d ? (NS - 3 - t) : (t + 2);
            gfut = *(const bf16x4*)(gbase + (size_t)(b * 512 + tt2) * 2048);
        }

        // MFMA: gates = Whh_i8 . h_i8 with K-quarter row masking
        v4i acc[2][4] = {};
        {
            v4i chunk = *(const v4i*)&hs[rb][hrd];
            v4i a[4];
#pragma unroll
            for (int kt = 0; kt < 4; kt++) {
                a[kt][0] = (rr == kt) ? chunk[0] : 0;
                a[kt][1] = (rr == kt) ? chunk[1] : 0;
                a[kt][2] = (rr == kt) ? chunk[2] : 0;
                a[kt][3] = (rr == kt) ? chunk[3] : 0;
            }
#pragma unroll
            for (int sl = 0; sl < 2; sl++)
#pragma unroll
                for (int g = 0; g < 4; g++)
#pragma unroll
                    for (int kt = 0; kt < 4; kt++)
                        acc[sl][g] = __builtin_amdgcn_mfma_i32_16x16x64_i8(a[kt], Wr[sl][g][kt], acc[sl][g], 0, 0, 0);
        }

        // elementwise: static acc indexing (rule #20) + cndmask select on jg
        int s[4];
#pragma unroll
        for (int g = 0; g < 4; g++) {
            int s0 = acc[0][g][0] + acc[0][g][1] + acc[0][g][2] + acc[0][g][3];
            int s1 = acc[1][g][0] + acc[1][g][1] + acc[1][g][2] + acc[1][g][3];
            s[g] = jg ? s1 : s0;
        }
        float pi = (float)s[0] * scv[0] + (float)gcur[0];
        float pf = (float)s[1] * scv[1] + (float)gcur[1];
        float pg = (float)s[2] * scv[2] + (float)gcur[2];
        float po = (float)s[3] * scv[3] + (float)gcur[3];
        float ig = sigm(pi), fg = sigm(pf), gc = tanh_(pg), og = sigm(po);
        float c = fg * cst + ig * gc;
        cst = c;
        float hh = og * tanh_(c);
        const int tcur = d ? (NS - 1 - t) : t;
        io_out[iob + (size_t)tcur * 512] = (bf16)hh;
        hs[wbuf][hwr] = (signed char)(int)__builtin_rintf(hh * 127.f);

        gcur = gnxt; gnxt = gfut;

        // raw barrier: drain ONLY lgkm (h ds_write visibility); VMEM stays in flight.
        asm volatile("s_waitcnt lgkmcnt(0)" ::: "memory");
        __builtin_amdgcn_s_barrier();
        asm volatile("" ::: "memory");
    }
}

// ---------------- fused GCN: C = A*W^T + bias + x -> rowLN -> relu -> f32 out ----------------
__global__ __launch_bounds__(256, 2)
void k_gcn_fused(const bf16* __restrict__ A,      // [32768][256] bf16 (banded out)
                 const bf16* __restrict__ W,      // [256][256] bf16
                 const float* __restrict__ bias,  // [256]
                 const float* __restrict__ x,     // [32768][256] f32 residual in
                 const float* __restrict__ gamma, const float* __restrict__ beta,
                 float* __restrict__ outx)        // [32768][256] f32
{
    __shared__ __align__(16) bf16 sA[128 * 64];
    __shared__ __align__(16) bf16 sB[2][128 * 64];
    __shared__ float lnred[2][128][2];
    const int m0 = blockIdx.x << 7;
    int tid = threadIdx.x;
    int wave = tid >> 6, lane = tid & 63;
    int wm = wave >> 1, wn = wave & 1;
    int l15 = lane & 15, quad = lane >> 4;

    f32x4 acc[2][4][4] = {};

    const int r0 = tid >> 3;
    const int c0 = (tid & 7) * 8;
    const bf16* Ab = A + (size_t)(m0 + r0) * 256 + c0;
    const bf16* Wb = W + (size_t)r0 * 256 + c0;
    bf16* sAd = sA + tid * 8;

    for (int k0 = 0; k0 < 256; k0 += 64) {
#pragma unroll
        for (int i = 0; i < 4; i++) {
            gload_lds16(Ab + (size_t)(i * 32) * 256 + k0, sAd + i * 2048);
            gload_lds16(Wb + (size_t)(i * 32) * 256 + k0, sB[0] + tid * 8 + i * 2048);
            gload_lds16(Wb + (size_t)(128 + i * 32) * 256 + k0, sB[1] + tid * 8 + i * 2048);
        }
        __syncthreads();
#pragma unroll
        for (int kk = 0; kk < 2; kk++) {
            bf16x8 af[4];
#pragma unroll
            for (int mt = 0; mt < 4; mt++)
                af[mt] = *(const bf16x8*)(sA + (wm * 64 + mt * 16 + l15) * 64 + kk * 32 + quad * 8);
#pragma unroll
            for (int bn = 0; bn < 2; bn++) {
                bf16x8 bfr[4];
#pragma unroll
                for (int nt = 0; nt < 4; nt++)
                    bfr[nt] = *(const bf16x8*)(sB[bn] + (wn * 64 + nt * 16 + l15) * 64 + kk * 32 + quad * 8);
#pragma unroll
                for (int mt = 0; mt < 4; mt++)
#pragma unroll
                    for (int nt = 0; nt < 4; nt++)
                        acc[bn][mt][nt] = __builtin_amdgcn_mfma_f32_16x16x32_bf16(af[mt], bfr[nt], acc[bn][mt][nt], 0, 0, 0);
            }
        }
        __syncthreads();
    }

    float psum[4][4], psq[4][4];   // [mt][r4]
#pragma unroll
    for (int mt = 0; mt < 4; mt++)
#pragma unroll
        for (int r4 = 0; r4 < 4; r4++) { psum[mt][r4] = 0.f; psq[mt][r4] = 0.f; }

#pragma unroll
    for (int bn = 0; bn < 2; bn++)
#pragma unroll
        for (int nt = 0; nt < 4; nt++) {
            int col = bn * 128 + wn * 64 + nt * 16 + l15;
            float bv = bias[col];
#pragma unroll
            for (int mt = 0; mt < 4; mt++) {
                int row0 = m0 + wm * 64 + mt * 16 + quad * 4;
#pragma unroll
                for (int r4 = 0; r4 < 4; r4++) {
                    float v = acc[bn][mt][nt][r4] + bv + x[(size_t)(row0 + r4) * 256 + col];
                    acc[bn][mt][nt][r4] = v;
                    psum[mt][r4] += v;
                    psq[mt][r4]  += v * v;
                }
            }
        }
#pragma unroll
    for (int mt = 0; mt < 4; mt++)
#pragma unroll
        for (int r4 = 0; r4 < 4; r4++) {
#pragma unroll
            for (int off = 8; off >= 1; off >>= 1) {
                psum[mt][r4] += __shfl_xor(psum[mt][r4], off);
                psq[mt][r4]  += __shfl_xor(psq[mt][r4], off);
            }
        }
    if (l15 == 0) {
#pragma unroll
        for (int mt = 0; mt < 4; mt++)
#pragma unroll
            for (int r4 = 0; r4 < 4; r4++) {
                int rl = wm * 64 + mt * 16 + quad * 4 + r4;
                lnred[wn][rl][0] = psum[mt][r4];
                lnred[wn][rl][1] = psq[mt][r4];
            }
    }
    __syncthreads();
#pragma unroll
    for (int mt = 0; mt < 4; mt++) {
        int rl0 = wm * 64 + mt * 16 + quad * 4;
#pragma unroll
        for (int r4 = 0; r4 < 4; r4++) {
            float s  = lnred[0][rl0 + r4][0] + lnred[1][rl0 + r4][0];
            float sq = lnred[0][rl0 + r4][1] + lnred[1][rl0 + r4][1];
            float mu = s * (1.f / 256.f);
            float var = sq * (1.f / 256.f) - mu * mu;
            psum[mt][r4] = mu;
            psq[mt][r4]  = rsqrtf(var + 1e-5f);
        }
    }
#pragma unroll
    for (int bn = 0; bn < 2; bn++)
#pragma unroll
        for (int nt = 0; nt < 4; nt++) {
            int col = bn * 128 + wn * 64 + nt * 16 + l15;
            float gv = gamma[col], bv2 = beta[col];
#pragma unroll
            for (int mt = 0; mt < 4; mt++) {
                int row0 = m0 + wm * 64 + mt * 16 + quad * 4;
#pragma unroll
                for (int r4 = 0; r4 < 4; r4++) {
                    float y = (acc[bn][mt][nt][r4] - psum[mt][r4]) * psq[mt][r4] * gv + bv2;
                    outx[(size_t)(row0 + r4) * 256 + col] = fmaxf(y, 0.f);
                }
            }
        }
}

// ---------------- GCN banded adjacency matmul -> bf16 ----------------
__global__ void k_banded(const float* __restrict__ x, const float* __restrict__ mask,
                         bf16* __restrict__ outb) {
    int t  = blockIdx.x * 256 + threadIdx.x;  // < 64*512*64
    int bs = t >> 6;
    int c4 = (t & 63) << 2;
    int s = bs & (NS - 1);
    float m  = mask[bs];
    float mn = (s < NS - 1) ? mask[bs + 1] : 0.f;
    float mp = (s > 0)      ? mask[bs - 1] : 0.f;
    float rs = m * (mp + mn) + 1e-8f;
    float cn = m * mn / rs;
    float cp = m * mp / rs;
    f32x4 vn = {}, vp = {};
    if (s < NS - 1) vn = *(const f32x4*)(x + (size_t)(bs + 1) * NGC + c4);
    if (s > 0)      vp = *(const f32x4*)(x + (size_t)(bs - 1) * NGC + c4);
    bf16x4 o;
#pragma unroll
    for (int i = 0; i < 4; i++) o[i] = (bf16)(cn * vn[i] + cp * vp[i]);
    *(bf16x4*)(outb + (size_t)bs * NGC + c4) = o;
}

// ---------------- masked mean pooling ----------------
__global__ void k_pool_bf16(const bf16* __restrict__ src, const float* __restrict__ mask,
                            float* __restrict__ feat) {  // F = 512
    int b = blockIdx.x, f = threadIdx.x;
    float acc = 0.f, dm = 0.f;
    for (int t = 0; t < NS; t++) {
        float m = mask[b * NS + t];
        acc += m * (float)src[((size_t)b * NS + t) * 512 + f];
        dm += m;
    }
    feat[b * 512 + f] = acc / fmaxf(dm, 1e-8f);
}
__global__ void k_pool_f32(const float* __restrict__ src, const float* __restrict__ mask,
                           float* __restrict__ feat) {  // F = 256
    int b = blockIdx.x, f = threadIdx.x;
    float acc = 0.f, dm = 0.f;
    for (int t = 0; t < NS; t++) {
        float m = mask[b * NS + t];
        acc += m * src[((size_t)b * NS + t) * NGC + f];
        dm += m;
    }
    feat[b * NGC + f] = acc / fmaxf(dm, 1e-8f);
}

// ---------------- fused head ----------------
__global__ __launch_bounds__(512)
void k_head(const float* __restrict__ lfeat, const float* __restrict__ gfeat,
            const float* __restrict__ aux,
            const float* __restrict__ fc1W, const float* __restrict__ fc1b,
            const float* __restrict__ fc2W, const float* __restrict__ fc2b,
            const float* __restrict__ h0W, const float* __restrict__ h0b,
            const float* __restrict__ h1W, const float* __restrict__ h1b,
            float* __restrict__ out) {
    __shared__ float fused[FUSION];
    __shared__ float s1[512];
    __shared__ float s2[256];
    int m = blockIdx.x, tid = threadIdx.x;
    if (tid < 512) fused[tid] = lfeat[m * 512 + tid];
    if (tid < 256) fused[512 + tid] = gfeat[m * 256 + tid];
    if (tid < 6)   fused[768 + tid] = aux[m * 6 + tid];
    __syncthreads();
    {
        float a = fc1b[tid];
        const float* w = fc1W + (size_t)tid * FUSION;
        for (int k = 0; k < FUSION; k++) a += w[k] * fused[k];
        s1[tid] = fmaxf(a, 0.f);
    }
    __syncthreads();
    if (tid < 256) {
        float a = fc2b[tid];
        const float* w = fc2W + (size_t)tid * 512;
        for (int k = 0; k < 512; k++) a += w[k] * s1[k];
        s2[tid] = fmaxf(a, 0.f);
    }
    __syncthreads();
    if (tid < 15) {
        if (tid < 10) {
            float a = h0b[tid];
            const float* w = h0W + (size_t)tid * 256;
            for (int k = 0; k < 256; k++) a += w[k] * s2[k];
            out[m * 10 + tid] = a;
        } else {
            int n = tid - 10;
            float a = h1b[n];
            const float* w = h1W + (size_t)n * 256;
            for (int k = 0; k < 256; k++) a += w[k] * s2[k];
            out[640 + m * 5 + n] = a;
        }
    }
}

// ---------------- host launcher ----------------
extern "C" void kernel_launch(void* const* d_in, const int* in_sizes, int n_in,
                              void* d_out, int out_size, void* d_ws, size_t ws_size,
                              hipStream_t stream) {
    const int*   seq   = (const int*)d_in[0];
    const float* mask  = (const float*)d_in[1];
    const float* aux   = (const float*)d_in[2];
    const float* table = (const float*)d_in[3];
    const float* Wih0  = (const float*)d_in[4];
    const float* Whh0  = (const float*)d_in[5];
    const float* b0    = (const float*)d_in[6];
    const float* WihL  = (const float*)d_in[7];
    const float* WhhL  = (const float*)d_in[8];
    const float* bL    = (const float*)d_in[9];
    const float* gcnW  = (const float*)d_in[10];
    const float* gcnb  = (const float*)d_in[11];
    const float* gcnG  = (const float*)d_in[12];
    const float* gcnBe = (const float*)d_in[13];
    const float* fc1W  = (const float*)d_in[14];
    const float* fc1b  = (const float*)d_in[15];
    const float* fc2W  = (const float*)d_in[16];
    const float* fc2b  = (const float*)d_in[17];
    const float* h0W   = (const float*)d_in[18];
    const float* h0b   = (const float*)d_in[19];
    const float* h1W   = (const float*)d_in[20];
    const float* h1b   = (const float*)d_in[21];
    float* outp = (float*)d_out;

    char* ws = (char*)d_ws;
    const size_t MROWS = (size_t)NB * NS;          // 32768
    signed char* Wp8 = (signed char*)(ws + 0);     // 2.62 MB
    float* wsc     = (float*)(ws + 2621440);       // 40 KB
    bf16*  Wbf     = (bf16*) (ws + 2662400);       // 9.83 MB
    bf16*  wb0     = Wbf;                          // [2048][256] permuted
    bf16*  wbL     = Wbf + 524288;                 // 4 x [2048][512] permuted
    bf16*  wgcn    = Wbf + 524288 + 4194304;       // 3 x [256][256]
    bf16*  emb_b   = (bf16*) (ws + 33554432);      // 16.78 MB
    bf16*  io0     = (bf16*) (ws + 50331648);      // 33.55 MB
    bf16*  io1     = (bf16*) (ws + 83886080);      // 33.55 MB
    char*  Greg    =          ws + 117440512;      // 134.2 MB (G row-major bf16 [32768][2048])
    bf16*  G       = (bf16*)  Greg;
    float* lfeat   = (float*)(ws + 251658240);     // 128 KB
    float* gfeat   = (float*)(ws + 251789312);     // 64 KB
    float* pbias   = (float*)(ws + 251854848);     // 40 KB: permuted LSTM biases [5][2048]
    unsigned int* flags = (unsigned int*)(ws + 251895808);  // 5 KB: [5][256] tile counters
    // GCN aliases (all inside Greg, used before G is written):
    float* gcnA  = (float*)(Greg + 0);
    float* gcnB_ = (float*)(Greg + 33554432);
    bf16*  gtmp  = (bf16*) (Greg + 100663296);
    (void)ws_size; (void)n_in; (void)in_sizes; (void)out_size;

    // ---- weight prep (same every call) ----
    k_cvt_perm<<<dim3(512),  dim3(256), 0, stream>>>(Wih0, wb0, 256, 2048);
    k_cvt_perm<<<dim3(2048), dim3(256), 0, stream>>>(WihL, wbL, 512, 8192);
    k_perm_bias<<<dim3(40), dim3(256), 0, stream>>>(b0, bL, pbias);
    k_cvt<<<dim3(192),  dim3(256), 0, stream>>>(gcnW, wgcn, 49152);
    k_prep_i8<<<dim3(2560), dim3(256), 0, stream>>>(Whh0, WhhL, Wp8, wsc);
    hipMemsetAsync(flags, 0, 5 * 256 * sizeof(unsigned int), stream);

    // embedding (f32 copy into gcnA, bf16 copy into emb_b)
    k_embed<<<dim3(8192), dim3(256), 0, stream>>>(seq, table, gcnA, emb_b);

    // ---- GCN stack (banded -> fused gemm+residual+LN+relu) ----
    const float* xcur = gcnA;
    float* xnxt[3] = {gcnB_, gcnA, gcnB_};
    for (int i = 0; i < 3; i++) {
        k_banded<<<dim3(8192), dim3(256), 0, stream>>>(xcur, mask, gtmp);
        k_gcn_fused<<<dim3(MROWS / 128), dim3(256), 0, stream>>>(
            gtmp, wgcn + (size_t)i * NGC * NGC, gcnb + i * NGC, xcur,
            gcnG + i * NGC, gcnBe + i * NGC, xnxt[i]);
        xcur = xnxt[i];
    }
    k_pool_f32<<<dim3(NB), dim3(NGC), 0, stream>>>(xcur, mask, gfeat);

    // ---- BiLSTM stack: per layer, GEMM chunks{0,3} then fused LSTM + chunks{1,2} ----
    const bf16* Xin = emb_b;
    int Kin = NE;
    bf16* ios[2] = {io0, io1};
    for (int l = 0; l < NL; l++) {
        const bf16* wih = l ? (wbL + (size_t)(l - 1) * 1048576) : wb0;
        bf16* lio = ios[l & 1];
        k_gemm_lstm03<<<dim3(2048), dim3(512), 0, stream>>>(
            Xin, wih, pbias + (size_t)l * 2048, G, Kin);
        k_lstm_fused<<<dim3(2112), dim3(512), 0, stream>>>(
            Xin, wih, pbias + (size_t)l * 2048, G,
            Wp8 + (size_t)l * 524288, wsc + (size_t)l * 2048, lio,
            flags + (size_t)l * 256, Kin);
        Xin = lio;
        Kin = 512;
    }
    k_pool_bf16<<<dim3(NB), dim3(512), 0, stream>>>(ios[(NL - 1) & 1], mask, lfeat);

    // ---- fused head ----
    k_head<<<dim3(NB), dim3(512), 0, stream>>>(
        lfeat, gfeat, aux, fc1W, fc1b, fc2W, fc2b, h0W, h0b, h1W, h1b, outp);
}

// Round 10
// 3167.096 us; speedup vs baseline: 1.1591x; 1.1591x over previous
//
#include <hip/hip_runtime.h>
#include <stdint.h>
#include <stddef.h>

// ---------------- types ----------------
typedef __bf16 bf16;
typedef __bf16 bf16x8 __attribute__((ext_vector_type(8)));
typedef __bf16 bf16x4 __attribute__((ext_vector_type(4)));
typedef float  f32x4  __attribute__((ext_vector_type(4)));
typedef int    v4i    __attribute__((ext_vector_type(4)));

// ---------------- problem constants ----------------
#define NB   64      // batch
#define NS   512     // seq len
#define NE   256     // embed dim
#define NH   256     // lstm hidden
#define NL   5       // lstm layers
#define NGC  256     // gcn hidden
#define FUSION 774   // 2H + GC + 6

__device__ __forceinline__ float sigm(float x) {
    return __fdividef(1.f, 1.f + __expf(-x));
}
__device__ __forceinline__ float tanh_(float x) {
    return __fdividef(2.f, 1.f + __expf(-2.f * x)) - 1.f;
}

// async global->LDS, 16B per lane. LDS dest must be wave-uniform base + lane*16.
__device__ __forceinline__ void gload_lds16(const void* g, void* l) {
    __builtin_amdgcn_global_load_lds(
        (const __attribute__((address_space(1))) void*)g,
        (__attribute__((address_space(3))) void*)l,
        16, 0, 0);
}

// ---------------- f32 -> bf16 convert (vector of 4) ----------------
__global__ void k_cvt(const float* __restrict__ src, bf16* __restrict__ dst, int n4) {
    int i = blockIdx.x * 256 + threadIdx.x;
    if (i >= n4) return;
    f32x4 v = ((const f32x4*)src)[i];
    bf16x4 o;
    o[0] = (bf16)v[0]; o[1] = (bf16)v[1]; o[2] = (bf16)v[2]; o[3] = (bf16)v[3];
    ((bf16x4*)dst)[i] = o;
}

// ---------------- Wih convert + gate-interleave row permute ----------------
// dst row n' = d*1024 + j*4 + g  <-  src row d*1024 + g*256 + j.
__global__ void k_cvt_perm(const float* __restrict__ src, bf16* __restrict__ dst,
                           int K, int nrows) {
    int r = blockIdx.x * 4 + (threadIdx.x >> 6);
    int lane = threadIdx.x & 63;
    if (r >= nrows) return;
    int g = r & 3, j = (r >> 2) & 255;
    int srcrow = (r & ~1023) | (g << 8) | j;
    const float* s = src + (size_t)srcrow * K;
    bf16* dp = dst + (size_t)r * K;
    for (int c = lane * 4; c < K; c += 256) {
        f32x4 v = *(const f32x4*)(s + c);
        bf16x4 o;
        o[0] = (bf16)v[0]; o[1] = (bf16)v[1]; o[2] = (bf16)v[2]; o[3] = (bf16)v[3];
        *(bf16x4*)(dp + c) = o;
    }
}

// bias permute to match: pb[l][n'] = src[l][d*1024 + g*256 + j]
__global__ void k_perm_bias(const float* __restrict__ b0, const float* __restrict__ bL,
                            float* __restrict__ pb) {
    int i = blockIdx.x * 256 + threadIdx.x;   // < 10240
    int r = i & 2047;
    int layer = i >> 11;
    int g = r & 3, j = (r >> 2) & 255, dh = r >> 10;
    int srcidx = dh * 1024 + g * 256 + j;
    float v = (layer == 0) ? b0[srcidx] : bL[(size_t)(layer - 1) * 2048 + srcidx];
    pb[i] = v;
}

// ---------------- embedding gather (f32 + bf16 copies) ----------------
__global__ void k_embed(const int* __restrict__ seq, const float* __restrict__ table,
                        float* __restrict__ ef, bf16* __restrict__ eb) {
    int t  = blockIdx.x * 256 + threadIdx.x;  // < 64*512*64
    int bs = t >> 6;
    int c4 = (t & 63) << 2;
    int row = seq[bs];
    f32x4 v = *(const f32x4*)(table + (size_t)row * NE + c4);
    *(f32x4*)(ef + (size_t)bs * NE + c4) = v;
    bf16x4 o;
    o[0] = (bf16)v[0]; o[1] = (bf16)v[1]; o[2] = (bf16)v[2]; o[3] = (bf16)v[3];
    *(bf16x4*)(eb + (size_t)bs * NE + c4) = o;
}

// ---------------- bf16 MFMA GEMM: C[M,N] = A[M,K] * W[N,K]^T + bias (both bf16) ----------------
// m97 structure: 128x128 tile, BK=64, linear LDS tiles staged via global_load_lds.
// XCD-chunked block swizzle, bn fastest within an XCD (R8-verified).
// R10: __launch_bounds__(256,3) — cap VGPR ~170 (m97 ran 164) to allow a 3rd
// resident block/CU; more wave-overlap across the per-K-step barrier drain.
// out_mode: 0 = f32 [M,N]; 1 = bf16 [M,N] row-major (coalesced 2B stores).
__global__ __launch_bounds__(256, 3)
void k_gemm(const bf16* __restrict__ A, const bf16* __restrict__ W,
            const float* __restrict__ bias, void* __restrict__ Cout,
            int M, int N, int K, int out_mode) {
    __shared__ __align__(16) bf16 sA[128 * 64];
    __shared__ __align__(16) bf16 sB[128 * 64];
    const int mblk = M >> 7, nblk = N >> 7;
    int bid = blockIdx.x;
    int bm, bn;
    if ((mblk & 7) == 0) {
        int xcd = bid & 7, r = bid >> 3;
        int bmo = r / nblk;
        bm = xcd * (mblk >> 3) + bmo;
        bn = r - bmo * nblk;
    } else {
        bm = bid % mblk;
        bn = bid / mblk;
    }
    int m0 = bm << 7, n0 = bn << 7;
    int tid  = threadIdx.x;
    int wave = tid >> 6, lane = tid & 63;
    int wm = wave >> 1, wn = wave & 1;
    int l15 = lane & 15, quad = lane >> 4;

    f32x4 acc[4][4] = {};

    // staging geometry: element e = i*2048 + tid*8 -> row = i*32 + tid/8, col = (tid&7)*8
    const int r0 = tid >> 3;
    const int c0 = (tid & 7) * 8;
    const bf16* Ab = A + (size_t)(m0 + r0) * K + c0;
    const bf16* Wb = W + (size_t)(n0 + r0) * K + c0;
    bf16* sAd = sA + tid * 8;
    bf16* sBd = sB + tid * 8;

    for (int k0 = 0; k0 < K; k0 += 64) {
#pragma unroll
        for (int i = 0; i < 4; i++) {
            gload_lds16(Ab + (size_t)(i * 32) * K + k0, sAd + i * 2048);
            gload_lds16(Wb + (size_t)(i * 32) * K + k0, sBd + i * 2048);
        }
        __syncthreads();   // drains vmcnt -> tiles visible
#pragma unroll
        for (int kk = 0; kk < 2; kk++) {
            bf16x8 af[4], bfr[4];
#pragma unroll
            for (int mt = 0; mt < 4; mt++)
                af[mt] = *(const bf16x8*)(sA + (wm * 64 + mt * 16 + l15) * 64 + kk * 32 + quad * 8);
#pragma unroll
            for (int nt = 0; nt < 4; nt++)
                bfr[nt] = *(const bf16x8*)(sB + (wn * 64 + nt * 16 + l15) * 64 + kk * 32 + quad * 8);
#pragma unroll
            for (int mt = 0; mt < 4; mt++)
#pragma unroll
                for (int nt = 0; nt < 4; nt++)
                    acc[mt][nt] = __builtin_amdgcn_mfma_f32_16x16x32_bf16(af[mt], bfr[nt], acc[mt][nt], 0, 0, 0);
        }
        __syncthreads();
    }
#pragma unroll
    for (int mt = 0; mt < 4; mt++) {
#pragma unroll
        for (int nt = 0; nt < 4; nt++) {
            int col = n0 + wn * 64 + nt * 16 + l15;
            float bv = bias[col];
            int row0 = m0 + wm * 64 + mt * 16 + quad * 4;
#pragma unroll
            for (int r4 = 0; r4 < 4; r4++) {
                float v = acc[mt][nt][r4] + bv;
                int r = row0 + r4;
                if (out_mode == 1) {
                    ((bf16*)Cout)[(size_t)r * N + col] = (bf16)v;
                } else {
                    ((float*)Cout)[(size_t)r * N + col] = v;
                }
            }
        }
    }
}

// ---------------- fused GCN: C = A*W^T + bias + x -> rowLN -> relu -> f32 out ----------------
// 128x256 tile per block (full LN rows in-block); cross-wave (wn) row-reduce
// for LN via 2KB LDS. (R8-verified.)
__global__ __launch_bounds__(256, 2)
void k_gcn_fused(const bf16* __restrict__ A,      // [32768][256] bf16 (banded out)
                 const bf16* __restrict__ W,      // [256][256] bf16
                 const float* __restrict__ bias,  // [256]
                 const float* __restrict__ x,     // [32768][256] f32 residual in
                 const float* __restrict__ gamma, const float* __restrict__ beta,
                 float* __restrict__ outx)        // [32768][256] f32
{
    __shared__ __align__(16) bf16 sA[128 * 64];
    __shared__ __align__(16) bf16 sB[2][128 * 64];
    __shared__ float lnred[2][128][2];
    const int m0 = blockIdx.x << 7;
    int tid = threadIdx.x;
    int wave = tid >> 6, lane = tid & 63;
    int wm = wave >> 1, wn = wave & 1;
    int l15 = lane & 15, quad = lane >> 4;

    f32x4 acc[2][4][4] = {};

    const int r0 = tid >> 3;
    const int c0 = (tid & 7) * 8;
    const bf16* Ab = A + (size_t)(m0 + r0) * 256 + c0;
    const bf16* Wb = W + (size_t)r0 * 256 + c0;
    bf16* sAd = sA + tid * 8;

    for (int k0 = 0; k0 < 256; k0 += 64) {
#pragma unroll
        for (int i = 0; i < 4; i++) {
            gload_lds16(Ab + (size_t)(i * 32) * 256 + k0, sAd + i * 2048);
            gload_lds16(Wb + (size_t)(i * 32) * 256 + k0, sB[0] + tid * 8 + i * 2048);
            gload_lds16(Wb + (size_t)(128 + i * 32) * 256 + k0, sB[1] + tid * 8 + i * 2048);
        }
        __syncthreads();
#pragma unroll
        for (int kk = 0; kk < 2; kk++) {
            bf16x8 af[4];
#pragma unroll
            for (int mt = 0; mt < 4; mt++)
                af[mt] = *(const bf16x8*)(sA + (wm * 64 + mt * 16 + l15) * 64 + kk * 32 + quad * 8);
#pragma unroll
            for (int bn = 0; bn < 2; bn++) {
                bf16x8 bfr[4];
#pragma unroll
                for (int nt = 0; nt < 4; nt++)
                    bfr[nt] = *(const bf16x8*)(sB[bn] + (wn * 64 + nt * 16 + l15) * 64 + kk * 32 + quad * 8);
#pragma unroll
                for (int mt = 0; mt < 4; mt++)
#pragma unroll
                    for (int nt = 0; nt < 4; nt++)
                        acc[bn][mt][nt] = __builtin_amdgcn_mfma_f32_16x16x32_bf16(af[mt], bfr[nt], acc[bn][mt][nt], 0, 0, 0);
            }
        }
        __syncthreads();
    }

    float psum[4][4], psq[4][4];   // [mt][r4]
#pragma unroll
    for (int mt = 0; mt < 4; mt++)
#pragma unroll
        for (int r4 = 0; r4 < 4; r4++) { psum[mt][r4] = 0.f; psq[mt][r4] = 0.f; }

#pragma unroll
    for (int bn = 0; bn < 2; bn++)
#pragma unroll
        for (int nt = 0; nt < 4; nt++) {
            int col = bn * 128 + wn * 64 + nt * 16 + l15;
            float bv = bias[col];
#pragma unroll
            for (int mt = 0; mt < 4; mt++) {
                int row0 = m0 + wm * 64 + mt * 16 + quad * 4;
#pragma unroll
                for (int r4 = 0; r4 < 4; r4++) {
                    float v = acc[bn][mt][nt][r4] + bv + x[(size_t)(row0 + r4) * 256 + col];
                    acc[bn][mt][nt][r4] = v;
                    psum[mt][r4] += v;
                    psq[mt][r4]  += v * v;
                }
            }
        }
#pragma unroll
    for (int mt = 0; mt < 4; mt++)
#pragma unroll
        for (int r4 = 0; r4 < 4; r4++) {
#pragma unroll
            for (int off = 8; off >= 1; off >>= 1) {
                psum[mt][r4] += __shfl_xor(psum[mt][r4], off);
                psq[mt][r4]  += __shfl_xor(psq[mt][r4], off);
            }
        }
    if (l15 == 0) {
#pragma unroll
        for (int mt = 0; mt < 4; mt++)
#pragma unroll
            for (int r4 = 0; r4 < 4; r4++) {
                int rl = wm * 64 + mt * 16 + quad * 4 + r4;
                lnred[wn][rl][0] = psum[mt][r4];
                lnred[wn][rl][1] = psq[mt][r4];
            }
    }
    __syncthreads();
#pragma unroll
    for (int mt = 0; mt < 4; mt++) {
        int rl0 = wm * 64 + mt * 16 + quad * 4;
#pragma unroll
        for (int r4 = 0; r4 < 4; r4++) {
            float s  = lnred[0][rl0 + r4][0] + lnred[1][rl0 + r4][0];
            float sq = lnred[0][rl0 + r4][1] + lnred[1][rl0 + r4][1];
            float mu = s * (1.f / 256.f);
            float var = sq * (1.f / 256.f) - mu * mu;
            psum[mt][r4] = mu;
            psq[mt][r4]  = rsqrtf(var + 1e-5f);
        }
    }
#pragma unroll
    for (int bn = 0; bn < 2; bn++)
#pragma unroll
        for (int nt = 0; nt < 4; nt++) {
            int col = bn * 128 + wn * 64 + nt * 16 + l15;
            float gv = gamma[col], bv2 = beta[col];
#pragma unroll
            for (int mt = 0; mt < 4; mt++) {
                int row0 = m0 + wm * 64 + mt * 16 + quad * 4;
#pragma unroll
                for (int r4 = 0; r4 < 4; r4++) {
                    float y = (acc[bn][mt][nt][r4] - psum[mt][r4]) * psq[mt][r4] * gv + bv2;
                    outx[(size_t)(row0 + r4) * 256 + col] = fmaxf(y, 0.f);
                }
            }
        }
}

// ---------------- Whh int8 pre-pack + per-row scales ----------------
__global__ void k_prep_i8(const float* __restrict__ Whh0, const float* __restrict__ WhhL,
                          signed char* __restrict__ Wp8, float* __restrict__ scales) {
    int gw = blockIdx.x * 4 + (threadIdx.x >> 6);   // row id < 10240
    int lane = threadIdx.x & 63;
    int row = gw & 1023;
    int d = (gw >> 10) & 1;
    int layer = gw >> 11;
    const float* src = (layer == 0)
        ? (Whh0 + ((size_t)d * 1024 + row) * 256)
        : (WhhL + (((size_t)(layer - 1) * 2 + d) * 1024 + row) * 256);
    f32x4 v = *(const f32x4*)(src + lane * 4);
    float am = fmaxf(fmaxf(fabsf(v[0]), fabsf(v[1])), fmaxf(fabsf(v[2]), fabsf(v[3])));
#pragma unroll
    for (int off = 32; off >= 1; off >>= 1) am = fmaxf(am, __shfl_xor(am, off));
    am = fmaxf(am, 1e-8f);
    float inv = 127.f / am;
    int q0 = (int)__builtin_rintf(v[0] * inv);
    int q1 = (int)__builtin_rintf(v[1] * inv);
    int q2 = (int)__builtin_rintf(v[2] * inv);
    int q3 = (int)__builtin_rintf(v[3] * inv);
    uint32_t packed = (q0 & 255) | ((q1 & 255) << 8) | ((q2 & 255) << 16) | ((q3 & 255) << 24);
    int g = row >> 8, rem = row & 255;
    int w = rem >> 4, l15r = rem & 15;
    int k = lane * 4;
    int kt = k >> 6, q = (k >> 4) & 3, j = k & 15;
    size_t cell = ((size_t)layer * 2 + d) * 256 + (w * 4 + g) * 4 + kt;
    *(uint32_t*)(Wp8 + cell * 1024 + (q * 16 + l15r) * 16 + j) = packed;
    if (lane == 0)
        scales[((size_t)layer * 2 + d) * 1024 + row] = am * (1.f / (127.f * 127.f));
}

// ---------------- LSTM recurrence: 64 blocks x 512 threads (R7-verified, untouched) ----------------
__global__ __launch_bounds__(512, 2)
void k_lstm_i8(const bf16* __restrict__ G,     // [32768 rows = b*512+tt][2048]
               const signed char* __restrict__ Wp8,  // [2][256][1024] for this layer
               const float* __restrict__ sc,   // [2][1024]
               bf16* __restrict__ io_out)      // [64][S][512]
{
    __shared__ signed char hs[2][2 * 4 * 80];   // h dbuf: (b_loc*4 + kt)*80 + (j&63)

    const int d   = blockIdx.x & 1;
    const int bg  = blockIdx.x >> 1;      // 0..31 (batch pair)
    const int tid = threadIdx.x;
    const int w = tid >> 6, lane = tid & 63;
    const int l15 = lane & 15, quad = lane >> 4;
    const int b_loc = quad & 1;           // batch within pair
    const int jg    = quad >> 1;          // j-group select (0/1)
    const int b = bg * 2 + b_loc;         // global batch for this lane
    const int j = (w + jg * 8) * 16 + l15; // hidden index owned by this lane

    // resident weights: 2 j-slices x 4 gates x 4 K-windows x 16B = 128 VGPRs
    v4i Wr[2][4][4];
#pragma unroll
    for (int sl = 0; sl < 2; sl++) {
        const int ws = w + sl * 8;
        const signed char* wb = Wp8 + ((size_t)d * 256 + ws * 16) * 1024 + lane * 16;
#pragma unroll
        for (int g = 0; g < 4; g++)
#pragma unroll
            for (int kt = 0; kt < 4; kt++)
                Wr[sl][g][kt] = *(const v4i*)(wb + (g * 4 + kt) * 1024);
    }
    // pin: values become asm outputs -> cannot be rematerialized by reloading
#pragma unroll
    for (int sl = 0; sl < 2; sl++)
#pragma unroll
        for (int g = 0; g < 4; g++)
#pragma unroll
            for (int kt = 0; kt < 4; kt++)
                asm volatile("" : "+v"(Wr[sl][g][kt]));

    // combined scales (row scale / 127^2) for this lane's 4 gate rows (own j only)
    float scv[4];
#pragma unroll
    for (int g = 0; g < 4; g++)
        scv[g] = sc[d * 1024 + g * 256 + j];

    const bf16* gbase = G + d * 1024 + j * 4;              // + row*2048
    const size_t iob = (size_t)b * NS * 512 + d * 256 + j; // + tt*512

    // LDS h write: own cell -> addr (b_loc*4 + (j>>6))*80 + (j&63)
    const int hwr = (b_loc * 4 + (j >> 6)) * 80 + (j & 63);
    // LDS h read (A fragment): row r=l15 -> (b_r=(l15>>2)&1, kt_r=l15&3);
    // lane reads 16B at (b_r*4 + kt_r)*80 + quad*16
    const int hrd = (((l15 >> 2) & 1) * 4 + (l15 & 3)) * 80 + quad * 16;
    const int rr = l15 & 3;               // kt this A-row carries

    float cst = 0.f;

    // distance-2 G pipeline (row(t) = b*512 + tt(t), tt = d ? NS-1-t : t)
    bf16x4 gcur = *(const bf16x4*)(gbase + (size_t)(b * 512 + (d ? (NS - 1) : 0)) * 2048);
    bf16x4 gnxt = *(const bf16x4*)(gbase + (size_t)(b * 512 + (d ? (NS - 2) : 1)) * 2048);

    // ---- step 0 (no h yet: gates = G only) ----
    {
        bf16x4 gfut = *(const bf16x4*)(gbase + (size_t)(b * 512 + (d ? (NS - 3) : 2)) * 2048);
        float pi = (float)gcur[0];
        float pg = (float)gcur[2], po = (float)gcur[3];
        float ig = sigm(pi), gc = tanh_(pg), og = sigm(po);
        float c = ig * gc;
        cst = c;
        float hh = og * tanh_(c);
        const int tcur = d ? (NS - 1) : 0;
        io_out[iob + (size_t)tcur * 512] = (bf16)hh;
        hs[0][hwr] = (signed char)(int)__builtin_rintf(hh * 127.f);
        gcur = gnxt; gnxt = gfut;
        asm volatile("s_waitcnt lgkmcnt(0)" ::: "memory");
        __builtin_amdgcn_s_barrier();
        asm volatile("" ::: "memory");
    }

    for (int t = 1; t < NS; t++) {
        const int rb = (t + 1) & 1, wbuf = t & 1;

        // prefetch G for step t+2
        bf16x4 gfut = gcur;
        if (t + 2 < NS) {
            const int tt2 = d ? (NS - 3 - t) : (t + 2);
            gfut = *(const bf16x4*)(gbase + (size_t)(b * 512 + tt2) * 2048);
        }

        // MFMA: gates = Whh_i8 . h_i8 with K-quarter row masking
        v4i acc[2][4] = {};
        {
            v4i chunk = *(const v4i*)&hs[rb][hrd];
            v4i a[4];
#pragma unroll
            for (int kt = 0; kt < 4; kt++) {
                a[kt][0] = (rr == kt) ? chunk[0] : 0;
                a[kt][1] = (rr == kt) ? chunk[1] : 0;
                a[kt][2] = (rr == kt) ? chunk[2] : 0;
                a[kt][3] = (rr == kt) ? chunk[3] : 0;
            }
#pragma unroll
            for (int sl = 0; sl < 2; sl++)
#pragma unroll
                for (int g = 0; g < 4; g++)
#pragma unroll
                    for (int kt = 0; kt < 4; kt++)
                        acc[sl][g] = __builtin_amdgcn_mfma_i32_16x16x64_i8(a[kt], Wr[sl][g][kt], acc[sl][g], 0, 0, 0);
        }

        // elementwise: 1 unique cell/lane. STATIC acc indexing (rule #20):
        // sum both slices (compile-time indices), scalar cndmask select on jg.
        int s[4];
#pragma unroll
        for (int g = 0; g < 4; g++) {
            int s0 = acc[0][g][0] + acc[0][g][1] + acc[0][g][2] + acc[0][g][3];
            int s1 = acc[1][g][0] + acc[1][g][1] + acc[1][g][2] + acc[1][g][3];
            s[g] = jg ? s1 : s0;
        }
        float pi = (float)s[0] * scv[0] + (float)gcur[0];
        float pf = (float)s[1] * scv[1] + (float)gcur[1];
        float pg = (float)s[2] * scv[2] + (float)gcur[2];
        float po = (float)s[3] * scv[3] + (float)gcur[3];
        float ig = sigm(pi), fg = sigm(pf), gc = tanh_(pg), og = sigm(po);
        float c = fg * cst + ig * gc;
        cst = c;
        float hh = og * tanh_(c);
        const int tcur = d ? (NS - 1 - t) : t;
        io_out[iob + (size_t)tcur * 512] = (bf16)hh;
        hs[wbuf][hwr] = (signed char)(int)__builtin_rintf(hh * 127.f);

        gcur = gnxt; gnxt = gfut;

        // raw barrier: drain ONLY lgkm (h ds_write visibility); VMEM stays in flight.
        asm volatile("s_waitcnt lgkmcnt(0)" ::: "memory");
        __builtin_amdgcn_s_barrier();
        asm volatile("" ::: "memory");
    }
}

// ---------------- GCN banded adjacency matmul -> bf16 ----------------
__global__ void k_banded(const float* __restrict__ x, const float* __restrict__ mask,
                         bf16* __restrict__ outb) {
    int t  = blockIdx.x * 256 + threadIdx.x;  // < 64*512*64
    int bs = t >> 6;
    int c4 = (t & 63) << 2;
    int s = bs & (NS - 1);
    float m  = mask[bs];
    float mn = (s < NS - 1) ? mask[bs + 1] : 0.f;
    float mp = (s > 0)      ? mask[bs - 1] : 0.f;
    float rs = m * (mp + mn) + 1e-8f;
    float cn = m * mn / rs;
    float cp = m * mp / rs;
    f32x4 vn = {}, vp = {};
    if (s < NS - 1) vn = *(const f32x4*)(x + (size_t)(bs + 1) * NGC + c4);
    if (s > 0)      vp = *(const f32x4*)(x + (size_t)(bs - 1) * NGC + c4);
    bf16x4 o;
#pragma unroll
    for (int i = 0; i < 4; i++) o[i] = (bf16)(cn * vn[i] + cp * vp[i]);
    *(bf16x4*)(outb + (size_t)bs * NGC + c4) = o;
}

// ---------------- masked mean pooling ----------------
__global__ void k_pool_bf16(const bf16* __restrict__ src, const float* __restrict__ mask,
                            float* __restrict__ feat) {  // F = 512
    int b = blockIdx.x, f = threadIdx.x;
    float acc = 0.f, dm = 0.f;
    for (int t = 0; t < NS; t++) {
        float m = mask[b * NS + t];
        acc += m * (float)src[((size_t)b * NS + t) * 512 + f];
        dm += m;
    }
    feat[b * 512 + f] = acc / fmaxf(dm, 1e-8f);
}
__global__ void k_pool_f32(const float* __restrict__ src, const float* __restrict__ mask,
                           float* __restrict__ feat) {  // F = 256
    int b = blockIdx.x, f = threadIdx.x;
    float acc = 0.f, dm = 0.f;
    for (int t = 0; t < NS; t++) {
        float m = mask[b * NS + t];
        acc += m * src[((size_t)b * NS + t) * NGC + f];
        dm += m;
    }
    feat[b * NGC + f] = acc / fmaxf(dm, 1e-8f);
}

// ---------------- fused head ----------------
__global__ __launch_bounds__(512)
void k_head(const float* __restrict__ lfeat, const float* __restrict__ gfeat,
            const float* __restrict__ aux,
            const float* __restrict__ fc1W, const float* __restrict__ fc1b,
            const float* __restrict__ fc2W, const float* __restrict__ fc2b,
            const float* __restrict__ h0W, const float* __restrict__ h0b,
            const float* __restrict__ h1W, const float* __restrict__ h1b,
            float* __restrict__ out) {
    __shared__ float fused[FUSION];
    __shared__ float s1[512];
    __shared__ float s2[256];
    int m = blockIdx.x, tid = threadIdx.x;
    if (tid < 512) fused[tid] = lfeat[m * 512 + tid];
    if (tid < 256) fused[512 + tid] = gfeat[m * 256 + tid];
    if (tid < 6)   fused[768 + tid] = aux[m * 6 + tid];
    __syncthreads();
    {
        float a = fc1b[tid];
        const float* w = fc1W + (size_t)tid * FUSION;
        for (int k = 0; k < FUSION; k++) a += w[k] * fused[k];
        s1[tid] = fmaxf(a, 0.f);
    }
    __syncthreads();
    if (tid < 256) {
        float a = fc2b[tid];
        const float* w = fc2W + (size_t)tid * 512;
        for (int k = 0; k < 512; k++) a += w[k] * s1[k];
        s2[tid] = fmaxf(a, 0.f);
    }
    __syncthreads();
    if (tid < 15) {
        if (tid < 10) {
            float a = h0b[tid];
            const float* w = h0W + (size_t)tid * 256;
            for (int k = 0; k < 256; k++) a += w[k] * s2[k];
            out[m * 10 + tid] = a;
        } else {
            int n = tid - 10;
            float a = h1b[n];
            const float* w = h1W + (size_t)n * 256;
            for (int k = 0; k < 256; k++) a += w[k] * s2[k];
            out[640 + m * 5 + n] = a;
        }
    }
}

// ---------------- host launcher ----------------
extern "C" void kernel_launch(void* const* d_in, const int* in_sizes, int n_in,
                              void* d_out, int out_size, void* d_ws, size_t ws_size,
                              hipStream_t stream) {
    const int*   seq   = (const int*)d_in[0];
    const float* mask  = (const float*)d_in[1];
    const float* aux   = (const float*)d_in[2];
    const float* table = (const float*)d_in[3];
    const float* Wih0  = (const float*)d_in[4];
    const float* Whh0  = (const float*)d_in[5];
    const float* b0    = (const float*)d_in[6];
    const float* WihL  = (const float*)d_in[7];
    const float* WhhL  = (const float*)d_in[8];
    const float* bL    = (const float*)d_in[9];
    const float* gcnW  = (const float*)d_in[10];
    const float* gcnb  = (const float*)d_in[11];
    const float* gcnG  = (const float*)d_in[12];
    const float* gcnBe = (const float*)d_in[13];
    const float* fc1W  = (const float*)d_in[14];
    const float* fc1b  = (const float*)d_in[15];
    const float* fc2W  = (const float*)d_in[16];
    const float* fc2b  = (const float*)d_in[17];
    const float* h0W   = (const float*)d_in[18];
    const float* h0b   = (const float*)d_in[19];
    const float* h1W   = (const float*)d_in[20];
    const float* h1b   = (const float*)d_in[21];
    float* outp = (float*)d_out;

    char* ws = (char*)d_ws;
    const size_t MROWS = (size_t)NB * NS;          // 32768
    signed char* Wp8 = (signed char*)(ws + 0);     // 2.62 MB
    float* wsc     = (float*)(ws + 2621440);       // 40 KB
    bf16*  Wbf     = (bf16*) (ws + 2662400);       // 9.83 MB
    bf16*  wb0     = Wbf;                          // [2048][256] permuted
    bf16*  wbL     = Wbf + 524288;                 // 4 x [2048][512] permuted
    bf16*  wgcn    = Wbf + 524288 + 4194304;       // 3 x [256][256]
    bf16*  emb_b   = (bf16*) (ws + 33554432);      // 16.78 MB
    bf16*  io0     = (bf16*) (ws + 50331648);      // 33.55 MB
    bf16*  io1     = (bf16*) (ws + 83886080);      // 33.55 MB
    char*  Greg    =          ws + 117440512;      // 134.2 MB (G row-major bf16 [32768][2048])
    bf16*  G       = (bf16*)  Greg;
    float* lfeat   = (float*)(ws + 251658240);     // 128 KB
    float* gfeat   = (float*)(ws + 251789312);     // 64 KB
    float* pbias   = (float*)(ws + 251854848);     // 40 KB: permuted LSTM biases [5][2048]
    // GCN aliases (all inside Greg, used before G is written):
    float* gcnA  = (float*)(Greg + 0);
    float* gcnB_ = (float*)(Greg + 33554432);
    bf16*  gtmp  = (bf16*) (Greg + 100663296);
    (void)ws_size; (void)n_in; (void)in_sizes; (void)out_size;

    // ---- weight prep (same every call) ----
    k_cvt_perm<<<dim3(512),  dim3(256), 0, stream>>>(Wih0, wb0, 256, 2048);
    k_cvt_perm<<<dim3(2048), dim3(256), 0, stream>>>(WihL, wbL, 512, 8192);
    k_perm_bias<<<dim3(40), dim3(256), 0, stream>>>(b0, bL, pbias);
    k_cvt<<<dim3(192),  dim3(256), 0, stream>>>(gcnW, wgcn, 49152);
    k_prep_i8<<<dim3(2560), dim3(256), 0, stream>>>(Whh0, WhhL, Wp8, wsc);

    // embedding (f32 copy into gcnA, bf16 copy into emb_b)
    k_embed<<<dim3(8192), dim3(256), 0, stream>>>(seq, table, gcnA, emb_b);

    // ---- GCN stack (banded -> fused gemm+residual+LN+relu) ----
    const float* xcur = gcnA;
    float* xnxt[3] = {gcnB_, gcnA, gcnB_};
    for (int i = 0; i < 3; i++) {
        k_banded<<<dim3(8192), dim3(256), 0, stream>>>(xcur, mask, gtmp);
        k_gcn_fused<<<dim3(MROWS / 128), dim3(256), 0, stream>>>(
            gtmp, wgcn + (size_t)i * NGC * NGC, gcnb + i * NGC, xcur,
            gcnG + i * NGC, gcnBe + i * NGC, xnxt[i]);
        xcur = xnxt[i];
    }
    k_pool_f32<<<dim3(NB), dim3(NGC), 0, stream>>>(xcur, mask, gfeat);

    // ---- BiLSTM stack ----
    const bf16* Xin = emb_b;
    int Kin = NE;
    bf16* ios[2] = {io0, io1};
    for (int l = 0; l < NL; l++) {
        const bf16* wih = l ? (wbL + (size_t)(l - 1) * 1048576) : wb0;
        k_gemm<<<dim3((MROWS / 128) * (2048 / 128)), dim3(256), 0, stream>>>(
            Xin, wih, pbias + (size_t)l * 2048, G, (int)MROWS, 2048, Kin, 1);
        bf16* lio = ios[l & 1];
        k_lstm_i8<<<dim3(64), dim3(512), 0, stream>>>(
            G, Wp8 + (size_t)l * 524288, wsc + (size_t)l * 2048, lio);
        Xin = lio;
        Kin = 512;
    }
    k_pool_bf16<<<dim3(NB), dim3(512), 0, stream>>>(ios[(NL - 1) & 1], mask, lfeat);

    // ---- fused head ----
    k_head<<<dim3(NB), dim3(512), 0, stream>>>(
        lfeat, gfeat, aux, fc1W, fc1b, fc2W, fc2b, h0W, h0b, h1W, h1b, outp);
}

// Round 11
// 3070.094 us; speedup vs baseline: 1.1958x; 1.0316x over previous
//
#include <hip/hip_runtime.h>
#include <stdint.h>
#include <stddef.h>

// ---------------- types ----------------
typedef __bf16 bf16;
typedef __bf16 bf16x8 __attribute__((ext_vector_type(8)));
typedef __bf16 bf16x4 __attribute__((ext_vector_type(4)));
typedef float  f32x4  __attribute__((ext_vector_type(4)));
typedef int    v4i    __attribute__((ext_vector_type(4)));

// ---------------- problem constants ----------------
#define NB   64      // batch
#define NS   512     // seq len
#define NE   256     // embed dim
#define NH   256     // lstm hidden
#define NL   5       // lstm layers
#define NGC  256     // gcn hidden
#define FUSION 774   // 2H + GC + 6

__device__ __forceinline__ float sigm(float x) {
    return __fdividef(1.f, 1.f + __expf(-x));
}
__device__ __forceinline__ float tanh_(float x) {
    return __fdividef(2.f, 1.f + __expf(-2.f * x)) - 1.f;
}

// async global->LDS, 16B per lane. LDS dest must be wave-uniform base + lane*16.
__device__ __forceinline__ void gload_lds16(const void* g, void* l) {
    __builtin_amdgcn_global_load_lds(
        (const __attribute__((address_space(1))) void*)g,
        (__attribute__((address_space(3))) void*)l,
        16, 0, 0);
}

// ---------------- f32 -> bf16 convert (vector of 4) ----------------
__global__ void k_cvt(const float* __restrict__ src, bf16* __restrict__ dst, int n4) {
    int i = blockIdx.x * 256 + threadIdx.x;
    if (i >= n4) return;
    f32x4 v = ((const f32x4*)src)[i];
    bf16x4 o;
    o[0] = (bf16)v[0]; o[1] = (bf16)v[1]; o[2] = (bf16)v[2]; o[3] = (bf16)v[3];
    ((bf16x4*)dst)[i] = o;
}

// ---------------- Wih convert + gate-interleave row permute ----------------
// dst row n' = d*1024 + j*4 + g  <-  src row d*1024 + g*256 + j.
__global__ void k_cvt_perm(const float* __restrict__ src, bf16* __restrict__ dst,
                           int K, int nrows) {
    int r = blockIdx.x * 4 + (threadIdx.x >> 6);
    int lane = threadIdx.x & 63;
    if (r >= nrows) return;
    int g = r & 3, j = (r >> 2) & 255;
    int srcrow = (r & ~1023) | (g << 8) | j;
    const float* s = src + (size_t)srcrow * K;
    bf16* dp = dst + (size_t)r * K;
    for (int c = lane * 4; c < K; c += 256) {
        f32x4 v = *(const f32x4*)(s + c);
        bf16x4 o;
        o[0] = (bf16)v[0]; o[1] = (bf16)v[1]; o[2] = (bf16)v[2]; o[3] = (bf16)v[3];
        *(bf16x4*)(dp + c) = o;
    }
}

// bias permute to match: pb[l][n'] = src[l][d*1024 + g*256 + j]
__global__ void k_perm_bias(const float* __restrict__ b0, const float* __restrict__ bL,
                            float* __restrict__ pb) {
    int i = blockIdx.x * 256 + threadIdx.x;   // < 10240
    int r = i & 2047;
    int layer = i >> 11;
    int g = r & 3, j = (r >> 2) & 255, dh = r >> 10;
    int srcidx = dh * 1024 + g * 256 + j;
    float v = (layer == 0) ? b0[srcidx] : bL[(size_t)(layer - 1) * 2048 + srcidx];
    pb[i] = v;
}

// ---------------- embedding gather (f32 + bf16 copies) ----------------
__global__ void k_embed(const int* __restrict__ seq, const float* __restrict__ table,
                        float* __restrict__ ef, bf16* __restrict__ eb) {
    int t  = blockIdx.x * 256 + threadIdx.x;  // < 64*512*64
    int bs = t >> 6;
    int c4 = (t & 63) << 2;
    int row = seq[bs];
    f32x4 v = *(const f32x4*)(table + (size_t)row * NE + c4);
    *(f32x4*)(ef + (size_t)bs * NE + c4) = v;
    bf16x4 o;
    o[0] = (bf16)v[0]; o[1] = (bf16)v[1]; o[2] = (bf16)v[2]; o[3] = (bf16)v[3];
    *(bf16x4*)(eb + (size_t)bs * NE + c4) = o;
}

// ---------------- bf16 MFMA GEMM: C[M,N] = A[M,K] * W[N,K]^T + bias (both bf16) ----------------
// m97 structure: 128x128 tile, BK=64, linear LDS tiles staged via global_load_lds.
// XCD-chunked block swizzle, bn fastest within an XCD (R8-verified).
// out_mode: 0 = f32 [M,N]; 1 = bf16 [M,N] row-major (coalesced 2B stores).
__global__ __launch_bounds__(256, 3)
void k_gemm(const bf16* __restrict__ A, const bf16* __restrict__ W,
            const float* __restrict__ bias, void* __restrict__ Cout,
            int M, int N, int K, int out_mode) {
    __shared__ __align__(16) bf16 sA[128 * 64];
    __shared__ __align__(16) bf16 sB[128 * 64];
    const int mblk = M >> 7, nblk = N >> 7;
    int bid = blockIdx.x;
    int bm, bn;
    if ((mblk & 7) == 0) {
        int xcd = bid & 7, r = bid >> 3;
        int bmo = r / nblk;
        bm = xcd * (mblk >> 3) + bmo;
        bn = r - bmo * nblk;
    } else {
        bm = bid % mblk;
        bn = bid / mblk;
    }
    int m0 = bm << 7, n0 = bn << 7;
    int tid  = threadIdx.x;
    int wave = tid >> 6, lane = tid & 63;
    int wm = wave >> 1, wn = wave & 1;
    int l15 = lane & 15, quad = lane >> 4;

    f32x4 acc[4][4] = {};

    // staging geometry: element e = i*2048 + tid*8 -> row = i*32 + tid/8, col = (tid&7)*8
    const int r0 = tid >> 3;
    const int c0 = (tid & 7) * 8;
    const bf16* Ab = A + (size_t)(m0 + r0) * K + c0;
    const bf16* Wb = W + (size_t)(n0 + r0) * K + c0;
    bf16* sAd = sA + tid * 8;
    bf16* sBd = sB + tid * 8;

    for (int k0 = 0; k0 < K; k0 += 64) {
#pragma unroll
        for (int i = 0; i < 4; i++) {
            gload_lds16(Ab + (size_t)(i * 32) * K + k0, sAd + i * 2048);
            gload_lds16(Wb + (size_t)(i * 32) * K + k0, sBd + i * 2048);
        }
        __syncthreads();   // drains vmcnt -> tiles visible
#pragma unroll
        for (int kk = 0; kk < 2; kk++) {
            bf16x8 af[4], bfr[4];
#pragma unroll
            for (int mt = 0; mt < 4; mt++)
                af[mt] = *(const bf16x8*)(sA + (wm * 64 + mt * 16 + l15) * 64 + kk * 32 + quad * 8);
#pragma unroll
            for (int nt = 0; nt < 4; nt++)
                bfr[nt] = *(const bf16x8*)(sB + (wn * 64 + nt * 16 + l15) * 64 + kk * 32 + quad * 8);
#pragma unroll
            for (int mt = 0; mt < 4; mt++)
#pragma unroll
                for (int nt = 0; nt < 4; nt++)
                    acc[mt][nt] = __builtin_amdgcn_mfma_f32_16x16x32_bf16(af[mt], bfr[nt], acc[mt][nt], 0, 0, 0);
        }
        __syncthreads();
    }
#pragma unroll
    for (int mt = 0; mt < 4; mt++) {
#pragma unroll
        for (int nt = 0; nt < 4; nt++) {
            int col = n0 + wn * 64 + nt * 16 + l15;
            float bv = bias[col];
            int row0 = m0 + wm * 64 + mt * 16 + quad * 4;
#pragma unroll
            for (int r4 = 0; r4 < 4; r4++) {
                float v = acc[mt][nt][r4] + bv;
                int r = row0 + r4;
                if (out_mode == 1) {
                    ((bf16*)Cout)[(size_t)r * N + col] = (bf16)v;
                } else {
                    ((float*)Cout)[(size_t)r * N + col] = v;
                }
            }
        }
    }
}

// ---------------- fused GCN: C = A*W^T + bias + x -> rowLN -> relu -> f32 out ----------------
// 128x256 tile per block (full LN rows in-block); cross-wave (wn) row-reduce
// for LN via 2KB LDS. (R8-verified.)
__global__ __launch_bounds__(256, 2)
void k_gcn_fused(const bf16* __restrict__ A,      // [32768][256] bf16 (banded out)
                 const bf16* __restrict__ W,      // [256][256] bf16
                 const float* __restrict__ bias,  // [256]
                 const float* __restrict__ x,     // [32768][256] f32 residual in
                 const float* __restrict__ gamma, const float* __restrict__ beta,
                 float* __restrict__ outx)        // [32768][256] f32
{
    __shared__ __align__(16) bf16 sA[128 * 64];
    __shared__ __align__(16) bf16 sB[2][128 * 64];
    __shared__ float lnred[2][128][2];
    const int m0 = blockIdx.x << 7;
    int tid = threadIdx.x;
    int wave = tid >> 6, lane = tid & 63;
    int wm = wave >> 1, wn = wave & 1;
    int l15 = lane & 15, quad = lane >> 4;

    f32x4 acc[2][4][4] = {};

    const int r0 = tid >> 3;
    const int c0 = (tid & 7) * 8;
    const bf16* Ab = A + (size_t)(m0 + r0) * 256 + c0;
    const bf16* Wb = W + (size_t)r0 * 256 + c0;
    bf16* sAd = sA + tid * 8;

    for (int k0 = 0; k0 < 256; k0 += 64) {
#pragma unroll
        for (int i = 0; i < 4; i++) {
            gload_lds16(Ab + (size_t)(i * 32) * 256 + k0, sAd + i * 2048);
            gload_lds16(Wb + (size_t)(i * 32) * 256 + k0, sB[0] + tid * 8 + i * 2048);
            gload_lds16(Wb + (size_t)(128 + i * 32) * 256 + k0, sB[1] + tid * 8 + i * 2048);
        }
        __syncthreads();
#pragma unroll
        for (int kk = 0; kk < 2; kk++) {
            bf16x8 af[4];
#pragma unroll
            for (int mt = 0; mt < 4; mt++)
                af[mt] = *(const bf16x8*)(sA + (wm * 64 + mt * 16 + l15) * 64 + kk * 32 + quad * 8);
#pragma unroll
            for (int bn = 0; bn < 2; bn++) {
                bf16x8 bfr[4];
#pragma unroll
                for (int nt = 0; nt < 4; nt++)
                    bfr[nt] = *(const bf16x8*)(sB[bn] + (wn * 64 + nt * 16 + l15) * 64 + kk * 32 + quad * 8);
#pragma unroll
                for (int mt = 0; mt < 4; mt++)
#pragma unroll
                    for (int nt = 0; nt < 4; nt++)
                        acc[bn][mt][nt] = __builtin_amdgcn_mfma_f32_16x16x32_bf16(af[mt], bfr[nt], acc[bn][mt][nt], 0, 0, 0);
            }
        }
        __syncthreads();
    }

    float psum[4][4], psq[4][4];   // [mt][r4]
#pragma unroll
    for (int mt = 0; mt < 4; mt++)
#pragma unroll
        for (int r4 = 0; r4 < 4; r4++) { psum[mt][r4] = 0.f; psq[mt][r4] = 0.f; }

#pragma unroll
    for (int bn = 0; bn < 2; bn++)
#pragma unroll
        for (int nt = 0; nt < 4; nt++) {
            int col = bn * 128 + wn * 64 + nt * 16 + l15;
            float bv = bias[col];
#pragma unroll
            for (int mt = 0; mt < 4; mt++) {
                int row0 = m0 + wm * 64 + mt * 16 + quad * 4;
#pragma unroll
                for (int r4 = 0; r4 < 4; r4++) {
                    float v = acc[bn][mt][nt][r4] + bv + x[(size_t)(row0 + r4) * 256 + col];
                    acc[bn][mt][nt][r4] = v;
                    psum[mt][r4] += v;
                    psq[mt][r4]  += v * v;
                }
            }
        }
#pragma unroll
    for (int mt = 0; mt < 4; mt++)
#pragma unroll
        for (int r4 = 0; r4 < 4; r4++) {
#pragma unroll
            for (int off = 8; off >= 1; off >>= 1) {
                psum[mt][r4] += __shfl_xor(psum[mt][r4], off);
                psq[mt][r4]  += __shfl_xor(psq[mt][r4], off);
            }
        }
    if (l15 == 0) {
#pragma unroll
        for (int mt = 0; mt < 4; mt++)
#pragma unroll
            for (int r4 = 0; r4 < 4; r4++) {
                int rl = wm * 64 + mt * 16 + quad * 4 + r4;
                lnred[wn][rl][0] = psum[mt][r4];
                lnred[wn][rl][1] = psq[mt][r4];
            }
    }
    __syncthreads();
#pragma unroll
    for (int mt = 0; mt < 4; mt++) {
        int rl0 = wm * 64 + mt * 16 + quad * 4;
#pragma unroll
        for (int r4 = 0; r4 < 4; r4++) {
            float s  = lnred[0][rl0 + r4][0] + lnred[1][rl0 + r4][0];
            float sq = lnred[0][rl0 + r4][1] + lnred[1][rl0 + r4][1];
            float mu = s * (1.f / 256.f);
            float var = sq * (1.f / 256.f) - mu * mu;
            psum[mt][r4] = mu;
            psq[mt][r4]  = rsqrtf(var + 1e-5f);
        }
    }
#pragma unroll
    for (int bn = 0; bn < 2; bn++)
#pragma unroll
        for (int nt = 0; nt < 4; nt++) {
            int col = bn * 128 + wn * 64 + nt * 16 + l15;
            float gv = gamma[col], bv2 = beta[col];
#pragma unroll
            for (int mt = 0; mt < 4; mt++) {
                int row0 = m0 + wm * 64 + mt * 16 + quad * 4;
#pragma unroll
                for (int r4 = 0; r4 < 4; r4++) {
                    float y = (acc[bn][mt][nt][r4] - psum[mt][r4]) * psq[mt][r4] * gv + bv2;
                    outx[(size_t)(row0 + r4) * 256 + col] = fmaxf(y, 0.f);
                }
            }
        }
}

// ---------------- Whh int8 pre-pack + per-row scales ----------------
__global__ void k_prep_i8(const float* __restrict__ Whh0, const float* __restrict__ WhhL,
                          signed char* __restrict__ Wp8, float* __restrict__ scales) {
    int gw = blockIdx.x * 4 + (threadIdx.x >> 6);   // row id < 10240
    int lane = threadIdx.x & 63;
    int row = gw & 1023;
    int d = (gw >> 10) & 1;
    int layer = gw >> 11;
    const float* src = (layer == 0)
        ? (Whh0 + ((size_t)d * 1024 + row) * 256)
        : (WhhL + (((size_t)(layer - 1) * 2 + d) * 1024 + row) * 256);
    f32x4 v = *(const f32x4*)(src + lane * 4);
    float am = fmaxf(fmaxf(fabsf(v[0]), fabsf(v[1])), fmaxf(fabsf(v[2]), fabsf(v[3])));
#pragma unroll
    for (int off = 32; off >= 1; off >>= 1) am = fmaxf(am, __shfl_xor(am, off));
    am = fmaxf(am, 1e-8f);
    float inv = 127.f / am;
    int q0 = (int)__builtin_rintf(v[0] * inv);
    int q1 = (int)__builtin_rintf(v[1] * inv);
    int q2 = (int)__builtin_rintf(v[2] * inv);
    int q3 = (int)__builtin_rintf(v[3] * inv);
    uint32_t packed = (q0 & 255) | ((q1 & 255) << 8) | ((q2 & 255) << 16) | ((q3 & 255) << 24);
    int g = row >> 8, rem = row & 255;
    int w = rem >> 4, l15r = rem & 15;
    int k = lane * 4;
    int kt = k >> 6, q = (k >> 4) & 3, j = k & 15;
    size_t cell = ((size_t)layer * 2 + d) * 256 + (w * 4 + g) * 4 + kt;
    *(uint32_t*)(Wp8 + cell * 1024 + (q * 16 + l15r) * 16 + j) = packed;
    if (lane == 0)
        scales[((size_t)layer * 2 + d) * 1024 + row] = am * (1.f / (127.f * 127.f));
}

// ---------------- LSTM recurrence: 64 blocks x 512 threads ----------------
// R11: PRE-MASKED 4-region h LDS. The old per-step A-build (1 ds_read + 16
// v_cndmask on the critical path) is replaced by 4 ds_read_b128 from regions
// where the masked bytes are STATICALLY zero (zero-init once; each lane writes
// its byte to its 2 fixed rows per step, zeros never overwritten).
// Region kt: [16 rows(l15)][80B]; row l15 holds h[b=(l15>>2)&1][K-window kt]
// iff l15&3==kt, else zero. Also: running pointers for io_out and G prefetch
// (drop per-step tcur/addr recompute). Everything else is the R7-verified
// structure (64 blocks = 32 batch-pairs x 2 d, 2 same-d batches share Whh).
__global__ __launch_bounds__(512, 2)
void k_lstm_i8(const bf16* __restrict__ G,     // [32768 rows = b*512+tt][2048]
               const signed char* __restrict__ Wp8,  // [2][256][1024] for this layer
               const float* __restrict__ sc,   // [2][1024]
               bf16* __restrict__ io_out)      // [64][S][512]
{
    __shared__ signed char hs4[2][4][16 * 80];   // 2 dbuf x 4 kt-regions x 1280B

    const int d   = blockIdx.x & 1;
    const int bg  = blockIdx.x >> 1;      // 0..31 (batch pair)
    const int tid = threadIdx.x;
    const int w = tid >> 6, lane = tid & 63;
    const int l15 = lane & 15, quad = lane >> 4;
    const int b_loc = quad & 1;           // batch within pair
    const int jg    = quad >> 1;          // j-group select (0/1)
    const int b = bg * 2 + b_loc;         // global batch for this lane
    const int j = (w + jg * 8) * 16 + l15; // hidden index owned by this lane

    // zero-init the pre-masked regions (zeros persist: never overwritten)
    {
        int* p = (int*)hs4;
        for (int i = tid; i < (int)(sizeof(hs4) / 4); i += 512) p[i] = 0;
    }

    // resident weights: 2 j-slices x 4 gates x 4 K-windows x 16B = 128 VGPRs
    v4i Wr[2][4][4];
#pragma unroll
    for (int sl = 0; sl < 2; sl++) {
        const int ws = w + sl * 8;
        const signed char* wb = Wp8 + ((size_t)d * 256 + ws * 16) * 1024 + lane * 16;
#pragma unroll
        for (int g = 0; g < 4; g++)
#pragma unroll
            for (int kt = 0; kt < 4; kt++)
                Wr[sl][g][kt] = *(const v4i*)(wb + (g * 4 + kt) * 1024);
    }
    // pin: values become asm outputs -> cannot be rematerialized by reloading
#pragma unroll
    for (int sl = 0; sl < 2; sl++)
#pragma unroll
        for (int g = 0; g < 4; g++)
#pragma unroll
            for (int kt = 0; kt < 4; kt++)
                asm volatile("" : "+v"(Wr[sl][g][kt]));

    // combined scales (row scale / 127^2) for this lane's 4 gate rows (own j only)
    float scv[4];
#pragma unroll
    for (int g = 0; g < 4; g++)
        scv[g] = sc[d * 1024 + g * 256 + j];

    // h write: lane's h byte lives in region kt_own = j>>6, rows b_loc*4+kt_own
    // and +8 (row duplication for MFMA quad 2,3), byte j&63.
    const int kt_own = j >> 6;
    const int hwr0 = kt_own * 1280 + (b_loc * 4 + kt_own) * 80 + (j & 63);
    const int hwr1 = hwr0 + 640;          // +8 rows
    // h read (A fragments): per region, addr l15*80 + quad*16 (+ kt*1280 imm)
    const int hrd4 = l15 * 80 + quad * 16;

    float cst = 0.f;

    // running pointers: G row(t) = b*512 + tt(t), tt = d ? NS-1-t : t
    const bf16* gbase = G + d * 1024 + j * 4;
    const long gstep = (d ? -(long)2048 : (long)2048);
    bf16* iop = io_out + (size_t)b * NS * 512 + d * 256 + j
              + (size_t)(d ? (NS - 1) : 0) * 512;
    const long iostep = (d ? -(long)512 : (long)512);

    // distance-2 G pipeline
    bf16x4 gcur = *(const bf16x4*)(gbase + (size_t)(b * 512 + (d ? (NS - 1) : 0)) * 2048);
    bf16x4 gnxt = *(const bf16x4*)(gbase + (size_t)(b * 512 + (d ? (NS - 2) : 1)) * 2048);
    const bf16* gpt = gbase + (size_t)(b * 512 + (d ? (NS - 3) : 2)) * 2048;

    // ---- step 0 (no h yet: gates = G only) ----
    {
        bf16x4 gfut = *(const bf16x4*)gpt;
        gpt += gstep;
        float pi = (float)gcur[0];
        float pg = (float)gcur[2], po = (float)gcur[3];
        float ig = sigm(pi), gc = tanh_(pg), og = sigm(po);
        float c = ig * gc;
        cst = c;
        float hh = og * tanh_(c);
        *iop = (bf16)hh;
        iop += iostep;
        signed char hq = (signed char)(int)__builtin_rintf(hh * 127.f);
        hs4[0][0][hwr0] = hq;             // hwr0/1 include kt_own region offset
        hs4[0][0][hwr1] = hq;
        gcur = gnxt; gnxt = gfut;
        asm volatile("s_waitcnt lgkmcnt(0)" ::: "memory");
        __builtin_amdgcn_s_barrier();
        asm volatile("" ::: "memory");
    }

    for (int t = 1; t < NS; t++) {
        const int rb = (t + 1) & 1, wbuf = t & 1;

        // prefetch G for step t+2 (running pointer)
        bf16x4 gfut = gcur;
        if (t + 2 < NS) gfut = *(const bf16x4*)gpt;
        gpt += gstep;

        // MFMA: A fragments straight from pre-masked LDS (no VALU build)
        v4i a4[4];
        {
            const signed char* rbase = &hs4[rb][0][hrd4];
#pragma unroll
            for (int kt = 0; kt < 4; kt++)
                a4[kt] = *(const v4i*)(rbase + kt * 1280);
        }
        v4i acc[2][4] = {};
#pragma unroll
        for (int sl = 0; sl < 2; sl++)
#pragma unroll
            for (int g = 0; g < 4; g++)
#pragma unroll
                for (int kt = 0; kt < 4; kt++)
                    acc[sl][g] = __builtin_amdgcn_mfma_i32_16x16x64_i8(a4[kt], Wr[sl][g][kt], acc[sl][g], 0, 0, 0);

        // elementwise: 1 unique cell/lane. STATIC acc indexing (rule #20):
        // sum both slices (compile-time indices), scalar cndmask select on jg.
        int s[4];
#pragma unroll
        for (int g = 0; g < 4; g++) {
            int s0 = acc[0][g][0] + acc[0][g][1] + acc[0][g][2] + acc[0][g][3];
            int s1 = acc[1][g][0] + acc[1][g][1] + acc[1][g][2] + acc[1][g][3];
            s[g] = jg ? s1 : s0;
        }
        float pi = (float)s[0] * scv[0] + (float)gcur[0];
        float pf = (float)s[1] * scv[1] + (float)gcur[1];
        float pg = (float)s[2] * scv[2] + (float)gcur[2];
        float po = (float)s[3] * scv[3] + (float)gcur[3];
        float ig = sigm(pi), fg = sigm(pf), gc = tanh_(pg), og = sigm(po);
        float c = fg * cst + ig * gc;
        cst = c;
        float hh = og * tanh_(c);
        *iop = (bf16)hh;
        iop += iostep;
        signed char hq = (signed char)(int)__builtin_rintf(hh * 127.f);
        hs4[wbuf][0][hwr0] = hq;
        hs4[wbuf][0][hwr1] = hq;

        gcur = gnxt; gnxt = gfut;

        // raw barrier: drain ONLY lgkm (h ds_write visibility); VMEM stays in flight.
        asm volatile("s_waitcnt lgkmcnt(0)" ::: "memory");
        __builtin_amdgcn_s_barrier();
        asm volatile("" ::: "memory");
    }
}

// ---------------- GCN banded adjacency matmul -> bf16 ----------------
__global__ void k_banded(const float* __restrict__ x, const float* __restrict__ mask,
                         bf16* __restrict__ outb) {
    int t  = blockIdx.x * 256 + threadIdx.x;  // < 64*512*64
    int bs = t >> 6;
    int c4 = (t & 63) << 2;
    int s = bs & (NS - 1);
    float m  = mask[bs];
    float mn = (s < NS - 1) ? mask[bs + 1] : 0.f;
    float mp = (s > 0)      ? mask[bs - 1] : 0.f;
    float rs = m * (mp + mn) + 1e-8f;
    float cn = m * mn / rs;
    float cp = m * mp / rs;
    f32x4 vn = {}, vp = {};
    if (s < NS - 1) vn = *(const f32x4*)(x + (size_t)(bs + 1) * NGC + c4);
    if (s > 0)      vp = *(const f32x4*)(x + (size_t)(bs - 1) * NGC + c4);
    bf16x4 o;
#pragma unroll
    for (int i = 0; i < 4; i++) o[i] = (bf16)(cn * vn[i] + cp * vp[i]);
    *(bf16x4*)(outb + (size_t)bs * NGC + c4) = o;
}

// ---------------- masked mean pooling ----------------
__global__ void k_pool_bf16(const bf16* __restrict__ src, const float* __restrict__ mask,
                            float* __restrict__ feat) {  // F = 512
    int b = blockIdx.x, f = threadIdx.x;
    float acc = 0.f, dm = 0.f;
    for (int t = 0; t < NS; t++) {
        float m = mask[b * NS + t];
        acc += m * (float)src[((size_t)b * NS + t) * 512 + f];
        dm += m;
    }
    feat[b * 512 + f] = acc / fmaxf(dm, 1e-8f);
}
__global__ void k_pool_f32(const float* __restrict__ src, const float* __restrict__ mask,
                           float* __restrict__ feat) {  // F = 256
    int b = blockIdx.x, f = threadIdx.x;
    float acc = 0.f, dm = 0.f;
    for (int t = 0; t < NS; t++) {
        float m = mask[b * NS + t];
        acc += m * src[((size_t)b * NS + t) * NGC + f];
        dm += m;
    }
    feat[b * NGC + f] = acc / fmaxf(dm, 1e-8f);
}

// ---------------- fused head ----------------
__global__ __launch_bounds__(512)
void k_head(const float* __restrict__ lfeat, const float* __restrict__ gfeat,
            const float* __restrict__ aux,
            const float* __restrict__ fc1W, const float* __restrict__ fc1b,
            const float* __restrict__ fc2W, const float* __restrict__ fc2b,
            const float* __restrict__ h0W, const float* __restrict__ h0b,
            const float* __restrict__ h1W, const float* __restrict__ h1b,
            float* __restrict__ out) {
    __shared__ float fused[FUSION];
    __shared__ float s1[512];
    __shared__ float s2[256];
    int m = blockIdx.x, tid = threadIdx.x;
    if (tid < 512) fused[tid] = lfeat[m * 512 + tid];
    if (tid < 256) fused[512 + tid] = gfeat[m * 256 + tid];
    if (tid < 6)   fused[768 + tid] = aux[m * 6 + tid];
    __syncthreads();
    {
        float a = fc1b[tid];
        const float* w = fc1W + (size_t)tid * FUSION;
        for (int k = 0; k < FUSION; k++) a += w[k] * fused[k];
        s1[tid] = fmaxf(a, 0.f);
    }
    __syncthreads();
    if (tid < 256) {
        float a = fc2b[tid];
        const float* w = fc2W + (size_t)tid * 512;
        for (int k = 0; k < 512; k++) a += w[k] * s1[k];
        s2[tid] = fmaxf(a, 0.f);
    }
    __syncthreads();
    if (tid < 15) {
        if (tid < 10) {
            float a = h0b[tid];
            const float* w = h0W + (size_t)tid * 256;
            for (int k = 0; k < 256; k++) a += w[k] * s2[k];
            out[m * 10 + tid] = a;
        } else {
            int n = tid - 10;
            float a = h1b[n];
            const float* w = h1W + (size_t)n * 256;
            for (int k = 0; k < 256; k++) a += w[k] * s2[k];
            out[640 + m * 5 + n] = a;
        }
    }
}

// ---------------- host launcher ----------------
extern "C" void kernel_launch(void* const* d_in, const int* in_sizes, int n_in,
                              void* d_out, int out_size, void* d_ws, size_t ws_size,
                              hipStream_t stream) {
    const int*   seq   = (const int*)d_in[0];
    const float* mask  = (const float*)d_in[1];
    const float* aux   = (const float*)d_in[2];
    const float* table = (const float*)d_in[3];
    const float* Wih0  = (const float*)d_in[4];
    const float* Whh0  = (const float*)d_in[5];
    const float* b0    = (const float*)d_in[6];
    const float* WihL  = (const float*)d_in[7];
    const float* WhhL  = (const float*)d_in[8];
    const float* bL    = (const float*)d_in[9];
    const float* gcnW  = (const float*)d_in[10];
    const float* gcnb  = (const float*)d_in[11];
    const float* gcnG  = (const float*)d_in[12];
    const float* gcnBe = (const float*)d_in[13];
    const float* fc1W  = (const float*)d_in[14];
    const float* fc1b  = (const float*)d_in[15];
    const float* fc2W  = (const float*)d_in[16];
    const float* fc2b  = (const float*)d_in[17];
    const float* h0W   = (const float*)d_in[18];
    const float* h0b   = (const float*)d_in[19];
    const float* h1W   = (const float*)d_in[20];
    const float* h1b   = (const float*)d_in[21];
    float* outp = (float*)d_out;

    char* ws = (char*)d_ws;
    const size_t MROWS = (size_t)NB * NS;          // 32768
    signed char* Wp8 = (signed char*)(ws + 0);     // 2.62 MB
    float* wsc     = (float*)(ws + 2621440);       // 40 KB
    bf16*  Wbf     = (bf16*) (ws + 2662400);       // 9.83 MB
    bf16*  wb0     = Wbf;                          // [2048][256] permuted
    bf16*  wbL     = Wbf + 524288;                 // 4 x [2048][512] permuted
    bf16*  wgcn    = Wbf + 524288 + 4194304;       // 3 x [256][256]
    bf16*  emb_b   = (bf16*) (ws + 33554432);      // 16.78 MB
    bf16*  io0     = (bf16*) (ws + 50331648);      // 33.55 MB
    bf16*  io1     = (bf16*) (ws + 83886080);      // 33.55 MB
    char*  Greg    =          ws + 117440512;      // 134.2 MB (G row-major bf16 [32768][2048])
    bf16*  G       = (bf16*)  Greg;
    float* lfeat   = (float*)(ws + 251658240);     // 128 KB
    float* gfeat   = (float*)(ws + 251789312);     // 64 KB
    float* pbias   = (float*)(ws + 251854848);     // 40 KB: permuted LSTM biases [5][2048]
    // GCN aliases (all inside Greg, used before G is written):
    float* gcnA  = (float*)(Greg + 0);
    float* gcnB_ = (float*)(Greg + 33554432);
    bf16*  gtmp  = (bf16*) (Greg + 100663296);
    (void)ws_size; (void)n_in; (void)in_sizes; (void)out_size;

    // ---- weight prep (same every call) ----
    k_cvt_perm<<<dim3(512),  dim3(256), 0, stream>>>(Wih0, wb0, 256, 2048);
    k_cvt_perm<<<dim3(2048), dim3(256), 0, stream>>>(WihL, wbL, 512, 8192);
    k_perm_bias<<<dim3(40), dim3(256), 0, stream>>>(b0, bL, pbias);
    k_cvt<<<dim3(192),  dim3(256), 0, stream>>>(gcnW, wgcn, 49152);
    k_prep_i8<<<dim3(2560), dim3(256), 0, stream>>>(Whh0, WhhL, Wp8, wsc);

    // embedding (f32 copy into gcnA, bf16 copy into emb_b)
    k_embed<<<dim3(8192), dim3(256), 0, stream>>>(seq, table, gcnA, emb_b);

    // ---- GCN stack (banded -> fused gemm+residual+LN+relu) ----
    const float* xcur = gcnA;
    float* xnxt[3] = {gcnB_, gcnA, gcnB_};
    for (int i = 0; i < 3; i++) {
        k_banded<<<dim3(8192), dim3(256), 0, stream>>>(xcur, mask, gtmp);
        k_gcn_fused<<<dim3(MROWS / 128), dim3(256), 0, stream>>>(
            gtmp, wgcn + (size_t)i * NGC * NGC, gcnb + i * NGC, xcur,
            gcnG + i * NGC, gcnBe + i * NGC, xnxt[i]);
        xcur = xnxt[i];
    }
    k_pool_f32<<<dim3(NB), dim3(NGC), 0, stream>>>(xcur, mask, gfeat);

    // ---- BiLSTM stack ----
    const bf16* Xin = emb_b;
    int Kin = NE;
    bf16* ios[2] = {io0, io1};
    for (int l = 0; l < NL; l++) {
        const bf16* wih = l ? (wbL + (size_t)(l - 1) * 1048576) : wb0;
        k_gemm<<<dim3((MROWS / 128) * (2048 / 128)), dim3(256), 0, stream>>>(
            Xin, wih, pbias + (size_t)l * 2048, G, (int)MROWS, 2048, Kin, 1);
        bf16* lio = ios[l & 1];
        k_lstm_i8<<<dim3(64), dim3(512), 0, stream>>>(
            G, Wp8 + (size_t)l * 524288, wsc + (size_t)l * 2048, lio);
        Xin = lio;
        Kin = 512;
    }
    k_pool_bf16<<<dim3(NB), dim3(512), 0, stream>>>(ios[(NL - 1) & 1], mask, lfeat);

    // ---- fused head ----
    k_head<<<dim3(NB), dim3(512), 0, stream>>>(
        lfeat, gfeat, aux, fc1W, fc1b, fc2W, fc2b, h0W, h0b, h1W, h1b, outp);
}